// Round 1
// baseline (7377.093 us; speedup 1.0000x reference)
//
#include <hip/hip_runtime.h>
#include <hip/hip_bf16.h>

namespace {
constexpr int kB  = 2;
constexpr int kS  = 2048;
constexpr int kE  = 1024;
constexpr int kNH = 8;
constexpr int kDH = 128;
constexpr int kE3 = 3 * kE;

constexpr int BM  = 64;   // q rows per block
constexpr int BN  = 32;   // kv cols per tile
constexpr int PAD = 132;  // padded row stride (floats): keeps float4 16B-aligned, cuts conflicts
}

// ---------------- Kernel 1: gate projections i_pre/f_pre ----------------
__global__ __launch_bounds__(256) void gates_kernel(
    const float* __restrict__ q, const float* __restrict__ k, const float* __restrict__ v,
    const float* __restrict__ iw, const float* __restrict__ ib,
    const float* __restrict__ fw, const float* __restrict__ fb,
    float* __restrict__ i_pre, float* __restrict__ f_pre) {
  const int token = blockIdx.x;          // b*S + s
  const int b = token >> 11;             // /2048
  const int s = token & 2047;
  const int tid = threadIdx.x;
  const float* __restrict__ qrow = q + (size_t)token * kE;
  const float* __restrict__ krow = k + (size_t)token * kE;
  const float* __restrict__ vrow = v + (size_t)token * kE;

  float acc[16];
#pragma unroll
  for (int i = 0; i < 16; ++i) acc[i] = 0.f;

  for (int e = tid; e < kE3; e += 256) {
    float g;
    if (e < kE)          g = qrow[e];
    else if (e < 2 * kE) g = krow[e - kE];
    else                 g = vrow[e - 2 * kE];
#pragma unroll
    for (int h = 0; h < kNH; ++h) {
      acc[h]     += g * iw[h * kE3 + e];
      acc[8 + h] += g * fw[h * kE3 + e];
    }
  }
#pragma unroll
  for (int i = 0; i < 16; ++i) {
    float x = acc[i];
#pragma unroll
    for (int off = 32; off > 0; off >>= 1) x += __shfl_down(x, off);
    acc[i] = x;
  }
  __shared__ float red[16][4];
  const int wave = tid >> 6, lane = tid & 63;
  if (lane == 0) {
#pragma unroll
    for (int i = 0; i < 16; ++i) red[i][wave] = acc[i];
  }
  __syncthreads();
  if (tid < 16) {
    const float sum = red[tid][0] + red[tid][1] + red[tid][2] + red[tid][3];
    const int h = tid & 7;
    const size_t idx = ((size_t)b * kNH + h) * kS + s;
    if (tid < 8) i_pre[idx] = sum + ib[h];
    else         f_pre[idx] = sum + fb[h];
  }
}

// ---------------- Kernel 2: per-(b,h) scans ----------------
// cs = cumsum(logsigmoid(f)); a[j] = i_pre[j] - cs[j]; M[i] = cummax(a);
// D[i,j] = exp(a[j] - M[i]);  norm floor nfl[i] = exp(-(cs[i]+M[i])).
__global__ __launch_bounds__(256) void scan_kernel(
    const float* __restrict__ i_pre, const float* __restrict__ f_pre,
    float* __restrict__ a_out, float* __restrict__ M_out, float* __restrict__ nfl_out) {
  const int bh = blockIdx.x;
  const int tid = threadIdx.x;
  __shared__ float buf[256];
  const float* __restrict__ fp = f_pre + (size_t)bh * kS;
  const float* __restrict__ ip = i_pre + (size_t)bh * kS;
  float carry_cs = 0.f;
  float carry_max = -1e30f;
  for (int chunk = 0; chunk < kS / 256; ++chunk) {
    const int s = chunk * 256 + tid;
    const float f = fp[s];
    const float lf = fminf(f, 0.f) - log1pf(expf(-fabsf(f)));
    buf[tid] = lf;
    __syncthreads();
    for (int off = 1; off < 256; off <<= 1) {
      const float t = (tid >= off) ? buf[tid - off] : 0.f;
      __syncthreads();
      buf[tid] += t;
      __syncthreads();
    }
    const float cs = carry_cs + buf[tid];
    const float chunk_sum = buf[255];
    const float av = ip[s] - cs;
    __syncthreads();
    buf[tid] = av;
    __syncthreads();
    for (int off = 1; off < 256; off <<= 1) {
      const float t = (tid >= off) ? buf[tid - off] : -1e30f;
      __syncthreads();
      buf[tid] = fmaxf(buf[tid], t);
      __syncthreads();
    }
    const float Mv = fmaxf(carry_max, buf[tid]);
    const float chunk_max = buf[255];
    const size_t idx = (size_t)bh * kS + s;
    a_out[idx]   = av;
    M_out[idx]   = Mv;
    nfl_out[idx] = expf(-(cs + Mv));
    carry_cs += chunk_sum;
    carry_max = fmaxf(carry_max, chunk_max);
    __syncthreads();
  }
}

// ---------------- Kernel 3: causal decayed attention + groupnorm ----------------
__global__ __launch_bounds__(256) void attn_kernel(
    const float* __restrict__ qg, const float* __restrict__ kg, const float* __restrict__ vg,
    const float* __restrict__ a_arr, const float* __restrict__ M_arr,
    const float* __restrict__ nfl_arr, const float* __restrict__ nw,
    float* __restrict__ out) {
  const int bh = blockIdx.y;
  const int b = bh >> 3;
  const int h = bh & 7;
  const int it = (int)gridDim.x - 1 - (int)blockIdx.x;   // heavy blocks dispatch first
  const int tid = threadIdx.x;
  const int tr = tid >> 4;   // 0..15  rows tr*4 .. tr*4+3
  const int tc = tid & 15;   // 0..15  cols tc*2,tc*2+1; dims tc*4 + 64k + m

  __shared__ float qs[BM * PAD];
  __shared__ float ks[BN * PAD];
  __shared__ float vs[BN * PAD];
  __shared__ float ss[BM * 33];
  __shared__ float aj[BN];

  const size_t bhS = (size_t)bh * kS;
  const int row0 = it * BM;

  // stage Q tile, pre-scaled by 1/sqrt(DH)
  {
    const float scale = 0.08838834764831845f;
    const size_t gbase = ((size_t)b * kS + row0) * kE + h * kDH;
#pragma unroll
    for (int w = 0; w < 8; ++w) {
      const int lin = w * 1024 + tid * 4;
      const int row = lin >> 7, col = lin & 127;
      float4 t = *reinterpret_cast<const float4*>(qg + gbase + (size_t)row * kE + col);
      t.x *= scale; t.y *= scale; t.z *= scale; t.w *= scale;
      *reinterpret_cast<float4*>(&qs[row * PAD + col]) = t;
    }
  }

  float Mrow[4];
#pragma unroll
  for (int i = 0; i < 4; ++i) Mrow[i] = M_arr[bhS + row0 + tr * 4 + i];

  float hacc[4][2][4];
#pragma unroll
  for (int i = 0; i < 4; ++i)
#pragma unroll
    for (int kk = 0; kk < 2; ++kk)
#pragma unroll
      for (int m = 0; m < 4; ++m) hacc[i][kk][m] = 0.f;
  float rs_part[4] = {0.f, 0.f, 0.f, 0.f};

  const int jt_max = 2 * it + 1;
  for (int jt = 0; jt <= jt_max; ++jt) {
    __syncthreads();   // all reads of ks/vs/ss from prev tile done
    {
      const size_t gbase = ((size_t)b * kS + jt * BN) * kE + h * kDH;
#pragma unroll
      for (int w = 0; w < 4; ++w) {
        const int lin = w * 1024 + tid * 4;
        const int row = lin >> 7, col = lin & 127;
        const size_t ga = gbase + (size_t)row * kE + col;
        *reinterpret_cast<float4*>(&ks[row * PAD + col]) =
            *reinterpret_cast<const float4*>(kg + ga);
        *reinterpret_cast<float4*>(&vs[row * PAD + col]) =
            *reinterpret_cast<const float4*>(vg + ga);
      }
    }
    if (tid < BN) aj[tid] = a_arr[bhS + jt * BN + tid];
    __syncthreads();

    // scores: 4 rows x 2 cols per thread, float4 over d
    float sreg[4][2];
#pragma unroll
    for (int i = 0; i < 4; ++i) { sreg[i][0] = 0.f; sreg[i][1] = 0.f; }
    {
      const float* __restrict__ qb = &qs[(tr * 4) * PAD];
      const float* __restrict__ kb = &ks[(tc * 2) * PAD];
      for (int d = 0; d < kDH; d += 4) {
        const float4 k0 = *reinterpret_cast<const float4*>(&kb[d]);
        const float4 k1 = *reinterpret_cast<const float4*>(&kb[PAD + d]);
#pragma unroll
        for (int i = 0; i < 4; ++i) {
          const float4 qv = *reinterpret_cast<const float4*>(&qb[i * PAD + d]);
          sreg[i][0] += qv.x * k0.x + qv.y * k0.y + qv.z * k0.z + qv.w * k0.w;
          sreg[i][1] += qv.x * k1.x + qv.y * k1.y + qv.z * k1.z + qv.w * k1.w;
        }
      }
    }
#pragma unroll
    for (int i = 0; i < 4; ++i) {
      const int ig = row0 + tr * 4 + i;
#pragma unroll
      for (int cc = 0; cc < 2; ++cc) {
        const int c = tc * 2 + cc;
        const int jg = jt * BN + c;
        float val = 0.f;
        if (jg <= ig) val = sreg[i][cc] * __expf(aj[c] - Mrow[i]);
        rs_part[i] += val;
        ss[(tr * 4 + i) * 33 + c] = val;
      }
    }
    __syncthreads();

    // PV: rows tr*4+i, dims tc*4 + 64*kk + m
#pragma unroll
    for (int c = 0; c < BN; ++c) {
      const float4 v0 = *reinterpret_cast<const float4*>(&vs[c * PAD + tc * 4]);
      const float4 v1 = *reinterpret_cast<const float4*>(&vs[c * PAD + tc * 4 + 64]);
#pragma unroll
      for (int i = 0; i < 4; ++i) {
        const float sc = ss[(tr * 4 + i) * 33 + c];
        hacc[i][0][0] += sc * v0.x; hacc[i][0][1] += sc * v0.y;
        hacc[i][0][2] += sc * v0.z; hacc[i][0][3] += sc * v0.w;
        hacc[i][1][0] += sc * v1.x; hacc[i][1][1] += sc * v1.y;
        hacc[i][1][2] += sc * v1.z; hacc[i][1][3] += sc * v1.w;
      }
    }
  }

  // epilogue: rowsum -> normalizer -> groupnorm; scratch aliased onto dead ks
  float* red = ks;
  __syncthreads();
#pragma unroll
  for (int i = 0; i < 4; ++i) red[(tr * 4 + i) * 16 + tc] = rs_part[i];
  __syncthreads();
  float inv[4];
#pragma unroll
  for (int i = 0; i < 4; ++i) {
    float rowsum = 0.f;
#pragma unroll
    for (int t = 0; t < 16; ++t) rowsum += red[(tr * 4 + i) * 16 + t];
    const float nf = nfl_arr[bhS + row0 + tr * 4 + i];
    inv[i] = 1.f / (fmaxf(fabsf(rowsum), nf) + 1e-6f);
  }
  __syncthreads();
#pragma unroll
  for (int i = 0; i < 4; ++i) {
    float ps = 0.f, pq = 0.f;
#pragma unroll
    for (int kk = 0; kk < 2; ++kk)
#pragma unroll
      for (int m = 0; m < 4; ++m) {
        const float hv = hacc[i][kk][m] * inv[i];
        hacc[i][kk][m] = hv;
        ps += hv; pq += hv * hv;
      }
    red[(tr * 4 + i) * 16 + tc] = ps;
    red[1024 + (tr * 4 + i) * 16 + tc] = pq;
  }
  __syncthreads();
#pragma unroll
  for (int i = 0; i < 4; ++i) {
    float mu = 0.f, m2 = 0.f;
#pragma unroll
    for (int t = 0; t < 16; ++t) {
      mu += red[(tr * 4 + i) * 16 + t];
      m2 += red[1024 + (tr * 4 + i) * 16 + t];
    }
    mu *= (1.f / 128.f);
    m2 *= (1.f / 128.f);
    const float rstd = rsqrtf(m2 - mu * mu + 1e-5f);
    float* __restrict__ orow = out + ((size_t)b * kS + row0 + tr * 4 + i) * kE + h * kDH;
    const float* __restrict__ nwh = nw + h * kDH;
#pragma unroll
    for (int kk = 0; kk < 2; ++kk) {
      const int d0 = tc * 4 + kk * 64;
      float4 o;
      o.x = (hacc[i][kk][0] - mu) * rstd * nwh[d0 + 0];
      o.y = (hacc[i][kk][1] - mu) * rstd * nwh[d0 + 1];
      o.z = (hacc[i][kk][2] - mu) * rstd * nwh[d0 + 2];
      o.w = (hacc[i][kk][3] - mu) * rstd * nwh[d0 + 3];
      *reinterpret_cast<float4*>(orow + d0) = o;
    }
  }
}

extern "C" void kernel_launch(void* const* d_in, const int* in_sizes, int n_in,
                              void* d_out, int out_size, void* d_ws, size_t ws_size,
                              hipStream_t stream) {
  const float* q  = (const float*)d_in[0];
  const float* k  = (const float*)d_in[1];
  const float* v  = (const float*)d_in[2];
  const float* iw = (const float*)d_in[3];
  const float* ib = (const float*)d_in[4];
  const float* fw = (const float*)d_in[5];
  const float* fb = (const float*)d_in[6];
  const float* nw = (const float*)d_in[7];
  float* out = (float*)d_out;
  float* ws  = (float*)d_ws;

  const int BHS = kB * kNH * kS;   // 32768
  float* i_pre = ws;
  float* f_pre = ws + BHS;
  float* a_arr = ws + 2 * BHS;
  float* M_arr = ws + 3 * BHS;
  float* nfl   = ws + 4 * BHS;     // 5*BHS*4 = 640 KB of ws

  gates_kernel<<<dim3(kB * kS), dim3(256), 0, stream>>>(q, k, v, iw, ib, fw, fb, i_pre, f_pre);
  scan_kernel<<<dim3(kB * kNH), dim3(256), 0, stream>>>(i_pre, f_pre, a_arr, M_arr, nfl);
  attn_kernel<<<dim3(kS / BM, kB * kNH), dim3(256), 0, stream>>>(q, k, v, a_arr, M_arr, nfl, nw, out);
}

// Round 2
// 282.976 us; speedup vs baseline: 26.0697x; 26.0697x over previous
//
#include <hip/hip_runtime.h>
#include <hip/hip_bf16.h>

typedef __attribute__((ext_vector_type(8))) short bf16x8;
typedef __attribute__((ext_vector_type(4))) float f32x4;

namespace {
constexpr int kB  = 2;
constexpr int kS  = 2048;
constexpr int kE  = 1024;
constexpr int kNH = 8;
constexpr int kDH = 128;
constexpr int kE3 = 3 * kE;

constexpr int BM = 64;   // q rows per block (4 waves x 16)
constexpr int BN = 64;   // kv cols per tile
}

__device__ __forceinline__ ushort f2bf(float x) {
  union { __hip_bfloat16 b; ushort u; } c;
  c.b = __float2bfloat16(x);
  return c.u;
}

// ---------------- Kernel 1: gate projections i_pre/f_pre ----------------
__global__ __launch_bounds__(256) void gates_kernel(
    const float* __restrict__ q, const float* __restrict__ k, const float* __restrict__ v,
    const float* __restrict__ iw, const float* __restrict__ ib,
    const float* __restrict__ fw, const float* __restrict__ fb,
    float* __restrict__ i_pre, float* __restrict__ f_pre) {
  const int token = blockIdx.x;
  const int b = token >> 11;
  const int s = token & 2047;
  const int tid = threadIdx.x;
  const float* __restrict__ qrow = q + (size_t)token * kE;
  const float* __restrict__ krow = k + (size_t)token * kE;
  const float* __restrict__ vrow = v + (size_t)token * kE;

  float acc[16];
#pragma unroll
  for (int i = 0; i < 16; ++i) acc[i] = 0.f;

  for (int e = tid; e < kE3; e += 256) {
    float g;
    if (e < kE)          g = qrow[e];
    else if (e < 2 * kE) g = krow[e - kE];
    else                 g = vrow[e - 2 * kE];
#pragma unroll
    for (int h = 0; h < kNH; ++h) {
      acc[h]     += g * iw[h * kE3 + e];
      acc[8 + h] += g * fw[h * kE3 + e];
    }
  }
#pragma unroll
  for (int i = 0; i < 16; ++i) {
    float x = acc[i];
#pragma unroll
    for (int off = 32; off > 0; off >>= 1) x += __shfl_down(x, off);
    acc[i] = x;
  }
  __shared__ float red[16][4];
  const int wave = tid >> 6, lane = tid & 63;
  if (lane == 0) {
#pragma unroll
    for (int i = 0; i < 16; ++i) red[i][wave] = acc[i];
  }
  __syncthreads();
  if (tid < 16) {
    const float sum = red[tid][0] + red[tid][1] + red[tid][2] + red[tid][3];
    const int h = tid & 7;
    const size_t idx = ((size_t)b * kNH + h) * kS + s;
    if (tid < 8) i_pre[idx] = sum + ib[h];
    else         f_pre[idx] = sum + fb[h];
  }
}

// ---------------- Kernel 2: per-(b,h) scans ----------------
__global__ __launch_bounds__(256) void scan_kernel(
    const float* __restrict__ i_pre, const float* __restrict__ f_pre,
    float* __restrict__ a_out, float* __restrict__ M_out, float* __restrict__ nfl_out) {
  const int bh = blockIdx.x;
  const int tid = threadIdx.x;
  __shared__ float buf[256];
  const float* __restrict__ fp = f_pre + (size_t)bh * kS;
  const float* __restrict__ ip = i_pre + (size_t)bh * kS;
  float carry_cs = 0.f;
  float carry_max = -1e30f;
  for (int chunk = 0; chunk < kS / 256; ++chunk) {
    const int s = chunk * 256 + tid;
    const float f = fp[s];
    const float lf = fminf(f, 0.f) - log1pf(expf(-fabsf(f)));
    buf[tid] = lf;
    __syncthreads();
    for (int off = 1; off < 256; off <<= 1) {
      const float t = (tid >= off) ? buf[tid - off] : 0.f;
      __syncthreads();
      buf[tid] += t;
      __syncthreads();
    }
    const float cs = carry_cs + buf[tid];
    const float chunk_sum = buf[255];
    const float av = ip[s] - cs;
    __syncthreads();
    buf[tid] = av;
    __syncthreads();
    for (int off = 1; off < 256; off <<= 1) {
      const float t = (tid >= off) ? buf[tid - off] : -1e30f;
      __syncthreads();
      buf[tid] = fmaxf(buf[tid], t);
      __syncthreads();
    }
    const float Mv = fmaxf(carry_max, buf[tid]);
    const float chunk_max = buf[255];
    const size_t idx = (size_t)bh * kS + s;
    a_out[idx]   = av;
    M_out[idx]   = Mv;
    nfl_out[idx] = expf(-(cs + Mv));
    carry_cs += chunk_sum;
    carry_max = fmaxf(carry_max, chunk_max);
    __syncthreads();
  }
}

// ---------------- Kernel 3: MFMA causal decayed attention + groupnorm ----------------
__global__ __launch_bounds__(256) void attn_mfma_kernel(
    const float* __restrict__ qg, const float* __restrict__ kg, const float* __restrict__ vg,
    const float* __restrict__ a_arr, const float* __restrict__ M_arr,
    const float* __restrict__ nfl_arr, const float* __restrict__ nw,
    float* __restrict__ out) {
  const int bh = blockIdx.y;
  const int b = bh >> 3, h = bh & 7;
  const int it = (int)gridDim.x - 1 - (int)blockIdx.x;  // heavy blocks first
  const int tid = threadIdx.x;
  const int w = tid >> 6, lane = tid & 63;
  const int l15 = lane & 15, g = lane >> 4;
  const int row0 = it * BM;
  const int rowbase = row0 + w * 16;
  const size_t bhS = (size_t)bh * kS;

  __shared__ ushort Klds[BN * kDH];     // [j][d] bf16, swizzled ^((j&7)<<4)
  __shared__ ushort Vt[kDH * BN];       // [d][j] bf16, swizzled ^(((d>>2)&7)<<4)
  __shared__ ushort Plds[4][16 * BN];   // per-wave [r][j], swizzled ^((r&7)<<4)
  __shared__ float aj[BN];

  // ---- Q fragments (scaled by 1/sqrt(DH)), hoisted for whole block ----
  bf16x8 qf[4];
  {
    const float scale = 0.08838834764831845f;
    const size_t qrow = ((size_t)b * kS + rowbase + l15) * kE + h * kDH;
#pragma unroll
    for (int ks = 0; ks < 4; ++ks) {
      const int d0 = ks * 32 + g * 8;
      const float4 lo = *reinterpret_cast<const float4*>(qg + qrow + d0);
      const float4 hi = *reinterpret_cast<const float4*>(qg + qrow + d0 + 4);
      bf16x8 f;
      f[0] = (short)f2bf(lo.x * scale); f[1] = (short)f2bf(lo.y * scale);
      f[2] = (short)f2bf(lo.z * scale); f[3] = (short)f2bf(lo.w * scale);
      f[4] = (short)f2bf(hi.x * scale); f[5] = (short)f2bf(hi.y * scale);
      f[6] = (short)f2bf(hi.z * scale); f[7] = (short)f2bf(hi.w * scale);
      qf[ks] = f;
    }
  }

  float Mrow[4];
#pragma unroll
  for (int reg = 0; reg < 4; ++reg) Mrow[reg] = M_arr[bhS + rowbase + g * 4 + reg];

  f32x4 hacc[8];
#pragma unroll
  for (int db = 0; db < 8; ++db) hacc[db] = (f32x4){0.f, 0.f, 0.f, 0.f};
  float rs[4] = {0.f, 0.f, 0.f, 0.f};

  for (int jt = 0; jt <= it; ++jt) {
    __syncthreads();  // previous tile fully consumed
    {
      const size_t kvbase = ((size_t)b * kS + jt * BN) * kE + h * kDH;
#pragma unroll
      for (int p = 0; p < 8; ++p) {
        const int j  = p * 8 + (tid >> 5);
        const int d0 = (tid & 31) * 4;
        const size_t ga = kvbase + (size_t)j * kE + d0;
        const float4 k4 = *reinterpret_cast<const float4*>(kg + ga);
        uint2 kp;
        kp.x = (uint)f2bf(k4.x) | ((uint)f2bf(k4.y) << 16);
        kp.y = (uint)f2bf(k4.z) | ((uint)f2bf(k4.w) << 16);
        int kb = j * 256 + d0 * 2; kb ^= ((j & 7) << 4);
        *reinterpret_cast<uint2*>(reinterpret_cast<char*>(Klds) + kb) = kp;

        const float4 v4 = *reinterpret_cast<const float4*>(vg + ga);
        const float vv[4] = {v4.x, v4.y, v4.z, v4.w};
#pragma unroll
        for (int m = 0; m < 4; ++m) {
          const int d = d0 + m;
          int vb = d * 128 + j * 2; vb ^= (((d >> 2) & 7) << 4);
          *reinterpret_cast<ushort*>(reinterpret_cast<char*>(Vt) + vb) = f2bf(vv[m]);
        }
      }
      if (tid < BN) aj[tid] = a_arr[bhS + jt * BN + tid];
    }
    __syncthreads();

    // ---- QK^T: S tile 16 x 64 per wave ----
    f32x4 sacc[4];
#pragma unroll
    for (int cb = 0; cb < 4; ++cb) sacc[cb] = (f32x4){0.f, 0.f, 0.f, 0.f};
#pragma unroll
    for (int ks = 0; ks < 4; ++ks) {
#pragma unroll
      for (int cb = 0; cb < 4; ++cb) {
        const int j = cb * 16 + l15;
        int kb = j * 256 + (ks * 32 + g * 8) * 2; kb ^= ((j & 7) << 4);
        const bf16x8 kf = *reinterpret_cast<const bf16x8*>(
            reinterpret_cast<const char*>(Klds) + kb);
        sacc[cb] = __builtin_amdgcn_mfma_f32_16x16x32_bf16(qf[ks], kf, sacc[cb], 0, 0, 0);
      }
    }

    // ---- decay * mask, rowsum, P -> bf16 LDS ----
    const int jbase = jt * BN;
    float av[4];
#pragma unroll
    for (int cb = 0; cb < 4; ++cb) av[cb] = aj[cb * 16 + l15];
#pragma unroll
    for (int cb = 0; cb < 4; ++cb) {
#pragma unroll
      for (int reg = 0; reg < 4; ++reg) {
        const int i = rowbase + g * 4 + reg;
        const int j = jbase + cb * 16 + l15;
        float val = 0.f;
        if (j <= i) val = sacc[cb][reg] * __expf(av[cb] - Mrow[reg]);
        rs[reg] += val;
        const int r = g * 4 + reg;
        int pb = r * 128 + (cb * 16 + l15) * 2; pb ^= ((r & 7) << 4);
        *reinterpret_cast<ushort*>(reinterpret_cast<char*>(&Plds[w][0]) + pb) = f2bf(val);
      }
    }

    // ---- PV: H += P * V ----
#pragma unroll
    for (int ks2 = 0; ks2 < 2; ++ks2) {
      int pb = l15 * 128 + (ks2 * 32 + g * 8) * 2; pb ^= ((l15 & 7) << 4);
      const bf16x8 pf = *reinterpret_cast<const bf16x8*>(
          reinterpret_cast<const char*>(&Plds[w][0]) + pb);
#pragma unroll
      for (int db = 0; db < 8; ++db) {
        const int d = db * 16 + l15;
        int vb = d * 128 + (ks2 * 32 + g * 8) * 2; vb ^= (((d >> 2) & 7) << 4);
        const bf16x8 vf = *reinterpret_cast<const bf16x8*>(
            reinterpret_cast<const char*>(Vt) + vb);
        hacc[db] = __builtin_amdgcn_mfma_f32_16x16x32_bf16(pf, vf, hacc[db], 0, 0, 0);
      }
    }
  }

  // ---- epilogue: rowsum reduce -> normalizer -> groupnorm -> store ----
#pragma unroll
  for (int reg = 0; reg < 4; ++reg) {
    float x = rs[reg];
    x += __shfl_xor(x, 1); x += __shfl_xor(x, 2);
    x += __shfl_xor(x, 4); x += __shfl_xor(x, 8);
    rs[reg] = x;
  }
  float inv[4];
#pragma unroll
  for (int reg = 0; reg < 4; ++reg) {
    const float nf = nfl_arr[bhS + rowbase + g * 4 + reg];
    inv[reg] = 1.f / (fmaxf(fabsf(rs[reg]), nf) + 1e-6f);
  }
  float ps[4] = {0.f, 0.f, 0.f, 0.f}, pq[4] = {0.f, 0.f, 0.f, 0.f};
#pragma unroll
  for (int db = 0; db < 8; ++db) {
#pragma unroll
    for (int reg = 0; reg < 4; ++reg) {
      const float hv = hacc[db][reg] * inv[reg];
      hacc[db][reg] = hv;
      ps[reg] += hv; pq[reg] += hv * hv;
    }
  }
#pragma unroll
  for (int reg = 0; reg < 4; ++reg) {
    float s1 = ps[reg], s2 = pq[reg];
    s1 += __shfl_xor(s1, 1); s1 += __shfl_xor(s1, 2);
    s1 += __shfl_xor(s1, 4); s1 += __shfl_xor(s1, 8);
    s2 += __shfl_xor(s2, 1); s2 += __shfl_xor(s2, 2);
    s2 += __shfl_xor(s2, 4); s2 += __shfl_xor(s2, 8);
    const float mu  = s1 * (1.f / 128.f);
    const float var = s2 * (1.f / 128.f) - mu * mu;
    const float rstd = rsqrtf(var + 1e-5f);
    const int i = rowbase + g * 4 + reg;
    float* __restrict__ orow = out + ((size_t)b * kS + i) * kE + h * kDH;
    const float* __restrict__ nwh = nw + h * kDH;
#pragma unroll
    for (int db = 0; db < 8; ++db) {
      const int d = db * 16 + l15;
      orow[d] = (hacc[db][reg] - mu) * rstd * nwh[d];
    }
  }
}

extern "C" void kernel_launch(void* const* d_in, const int* in_sizes, int n_in,
                              void* d_out, int out_size, void* d_ws, size_t ws_size,
                              hipStream_t stream) {
  const float* q  = (const float*)d_in[0];
  const float* k  = (const float*)d_in[1];
  const float* v  = (const float*)d_in[2];
  const float* iw = (const float*)d_in[3];
  const float* ib = (const float*)d_in[4];
  const float* fw = (const float*)d_in[5];
  const float* fb = (const float*)d_in[6];
  const float* nw = (const float*)d_in[7];
  float* out = (float*)d_out;
  float* ws  = (float*)d_ws;

  const int BHS = kB * kNH * kS;
  float* i_pre = ws;
  float* f_pre = ws + BHS;
  float* a_arr = ws + 2 * BHS;
  float* M_arr = ws + 3 * BHS;
  float* nfl   = ws + 4 * BHS;

  gates_kernel<<<dim3(kB * kS), dim3(256), 0, stream>>>(q, k, v, iw, ib, fw, fb, i_pre, f_pre);
  scan_kernel<<<dim3(kB * kNH), dim3(256), 0, stream>>>(i_pre, f_pre, a_arr, M_arr, nfl);
  attn_mfma_kernel<<<dim3(kS / BM, kB * kNH), dim3(256), 0, stream>>>(
      q, k, v, a_arr, M_arr, nfl, nw, out);
}

// Round 3
// 157.742 us; speedup vs baseline: 46.7669x; 1.7939x over previous
//
#include <hip/hip_runtime.h>
#include <hip/hip_bf16.h>
#include <math.h>

typedef __attribute__((ext_vector_type(8))) short bf16x8;
typedef __attribute__((ext_vector_type(4))) float f32x4;

namespace {
constexpr int kB = 2, kS = 2048, kE = 1024, kNH = 8, kDH = 128, kE3 = 3072;
constexpr float kLog2e = 1.4426950408889634f;
constexpr int BM = 64, BN = 64;
}

__device__ __forceinline__ ushort f2bf(float x) {
  union { __hip_bfloat16 b; ushort u; } c; c.b = __float2bfloat16(x); return c.u;
}

__device__ __forceinline__ void gload16(const void* g, void* l) {
  __builtin_amdgcn_global_load_lds(
      (const __attribute__((address_space(1))) void*)g,
      (__attribute__((address_space(3))) void*)l, 16, 0, 0);
}

// ---------------- conv: q,k -> bf16 head-major ----------------
__global__ __launch_bounds__(256) void convqk_kernel(
    const float* __restrict__ q, const float* __restrict__ k,
    ushort* __restrict__ Qb, ushort* __restrict__ Kb) {
  const size_t lin = ((size_t)blockIdx.x * 256 + threadIdx.x) * 8;
  const int b = (int)(lin >> 21);
  const int s = (int)((lin >> 10) & 2047);
  const int e = (int)(lin & 1023);
  const int h = e >> 7, d = e & 127;
  const size_t oidx = ((size_t)(b * 8 + h) * 2048 + s) * 128 + d;
  const float scale = 0.08838834764831845f;
  const float4 a0 = *reinterpret_cast<const float4*>(q + lin);
  const float4 a1 = *reinterpret_cast<const float4*>(q + lin + 4);
  bf16x8 pq;
  pq[0] = (short)f2bf(a0.x * scale); pq[1] = (short)f2bf(a0.y * scale);
  pq[2] = (short)f2bf(a0.z * scale); pq[3] = (short)f2bf(a0.w * scale);
  pq[4] = (short)f2bf(a1.x * scale); pq[5] = (short)f2bf(a1.y * scale);
  pq[6] = (short)f2bf(a1.z * scale); pq[7] = (short)f2bf(a1.w * scale);
  *reinterpret_cast<bf16x8*>(Qb + oidx) = pq;
  const float4 b0 = *reinterpret_cast<const float4*>(k + lin);
  const float4 b1 = *reinterpret_cast<const float4*>(k + lin + 4);
  bf16x8 pk;
  pk[0] = (short)f2bf(b0.x); pk[1] = (short)f2bf(b0.y);
  pk[2] = (short)f2bf(b0.z); pk[3] = (short)f2bf(b0.w);
  pk[4] = (short)f2bf(b1.x); pk[5] = (short)f2bf(b1.y);
  pk[6] = (short)f2bf(b1.z); pk[7] = (short)f2bf(b1.w);
  *reinterpret_cast<bf16x8*>(Kb + oidx) = pk;
}

// ---------------- conv: v -> bf16 transposed [b][h][d][s] ----------------
__global__ __launch_bounds__(256) void convv_kernel(
    const float* __restrict__ v, ushort* __restrict__ Vtb) {
  const int bh = blockIdx.x;
  const int b = bh >> 3, h = bh & 7;
  const int s0 = blockIdx.y * 256;
  const int tid = threadIdx.x;
  __shared__ ushort T[256 * 130];  // rows of 260 B (pad kills bank conflicts)
  const float* __restrict__ vsrc = v + ((size_t)b * 2048 + s0) * 1024 + h * 128;
#pragma unroll
  for (int iter = 0; iter < 16; ++iter) {
    const int gi = iter * 256 + tid;
    const int j = gi >> 4, d0 = (gi & 15) * 8;
    const float4 x0 = *reinterpret_cast<const float4*>(vsrc + (size_t)j * 1024 + d0);
    const float4 x1 = *reinterpret_cast<const float4*>(vsrc + (size_t)j * 1024 + d0 + 4);
    uint* dst = reinterpret_cast<uint*>(reinterpret_cast<char*>(T) + j * 260 + d0 * 2);
    dst[0] = (uint)f2bf(x0.x) | ((uint)f2bf(x0.y) << 16);
    dst[1] = (uint)f2bf(x0.z) | ((uint)f2bf(x0.w) << 16);
    dst[2] = (uint)f2bf(x1.x) | ((uint)f2bf(x1.y) << 16);
    dst[3] = (uint)f2bf(x1.z) | ((uint)f2bf(x1.w) << 16);
  }
  __syncthreads();
  const int dl = tid >> 2, qq = tid & 3;
#pragma unroll
  for (int dd = 0; dd < 2; ++dd) {
    const int d = dd * 64 + dl;
#pragma unroll
    for (int i = 0; i < 8; ++i) {
      const int j0 = i * 32 + qq * 8;
      const char* base = reinterpret_cast<const char*>(T) + d * 2;
      ushort e0 = *reinterpret_cast<const ushort*>(base + (j0 + 0) * 260);
      ushort e1 = *reinterpret_cast<const ushort*>(base + (j0 + 1) * 260);
      ushort e2 = *reinterpret_cast<const ushort*>(base + (j0 + 2) * 260);
      ushort e3 = *reinterpret_cast<const ushort*>(base + (j0 + 3) * 260);
      ushort e4 = *reinterpret_cast<const ushort*>(base + (j0 + 4) * 260);
      ushort e5 = *reinterpret_cast<const ushort*>(base + (j0 + 5) * 260);
      ushort e6 = *reinterpret_cast<const ushort*>(base + (j0 + 6) * 260);
      ushort e7 = *reinterpret_cast<const ushort*>(base + (j0 + 7) * 260);
      uint4 pk;
      pk.x = (uint)e0 | ((uint)e1 << 16);
      pk.y = (uint)e2 | ((uint)e3 << 16);
      pk.z = (uint)e4 | ((uint)e5 << 16);
      pk.w = (uint)e6 | ((uint)e7 << 16);
      *reinterpret_cast<uint4*>(Vtb + ((size_t)bh * 128 + d) * 2048 + s0 + j0) = pk;
    }
  }
}

// ---------------- gates: 4 tokens per block ----------------
__global__ __launch_bounds__(256) void gates_kernel(
    const float* __restrict__ q, const float* __restrict__ k, const float* __restrict__ v,
    const float* __restrict__ iw, const float* __restrict__ ib,
    const float* __restrict__ fw, const float* __restrict__ fb,
    float* __restrict__ i_pre, float* __restrict__ f_pre) {
  const int tid = threadIdx.x;
  const int wave = tid >> 6, lane = tid & 63;
  const int tokbase = blockIdx.x * 4;
  float acc[64];  // a = tok*16 + gate (0-7 i, 8-15 f)
#pragma unroll
  for (int i = 0; i < 64; ++i) acc[i] = 0.f;

  for (int step = 0; step < 12; ++step) {
    const int ebase = wave * 768 + step * 64;
    const int seg = ebase >> 10;
    const int eo = (ebase & 1023) + lane;
    const int e = ebase + lane;
    const float* __restrict__ src = (seg == 0) ? q : (seg == 1) ? k : v;
    float gv[4];
#pragma unroll
    for (int t = 0; t < 4; ++t)
      gv[t] = src[(size_t)(tokbase + t) * 1024 + eo];
    float wi[8], wf[8];
#pragma unroll
    for (int h = 0; h < 8; ++h) {
      wi[h] = iw[h * kE3 + e];
      wf[h] = fw[h * kE3 + e];
    }
#pragma unroll
    for (int t = 0; t < 4; ++t) {
#pragma unroll
      for (int h = 0; h < 8; ++h) {
        acc[t * 16 + h]     += gv[t] * wi[h];
        acc[t * 16 + 8 + h] += gv[t] * wf[h];
      }
    }
  }

  // compaction butterfly: reduce 64 accs across 64 lanes
  int cur = 64;
#pragma unroll
  for (int lv = 0; lv < 6; ++lv) {
    const int bmask = 1 << lv;
    const int half = cur >> 1;
    const bool hi = (lane & bmask) != 0;
#pragma unroll
    for (int i = 0; i < 32; ++i) {
      if (i >= half) break;
      const float keep = hi ? acc[i + half] : acc[i];
      const float send = hi ? acc[i] : acc[i + half];
      acc[i] = keep + __shfl_xor(send, bmask);
    }
    cur = half;
  }
  // lane holds total for a = bit-reversed lane
  const int a = ((lane & 1) << 5) | ((lane & 2) << 3) | ((lane & 4) << 1) |
                ((lane & 8) >> 1) | ((lane & 16) >> 3) | ((lane & 32) >> 5);
  __shared__ float red[4][64];
  red[wave][a] = acc[0];
  __syncthreads();
  if (tid < 64) {
    const float val = red[0][tid] + red[1][tid] + red[2][tid] + red[3][tid];
    const int tok = tid >> 4, gate = tid & 15, h = gate & 7;
    const int token = tokbase + tok;
    const int b = token >> 11, s = token & 2047;
    const size_t idx = ((size_t)(b * 8 + h)) * 2048 + s;
    if (gate < 8) i_pre[idx] = val + ib[h];
    else          f_pre[idx] = val + fb[h];
  }
}

// ---------------- scan: cs, a2 = (i_pre - cs)*log2e, M2 = cummax(a)*log2e, nfl ----------------
__global__ __launch_bounds__(256) void scan_kernel(
    const float* __restrict__ i_pre, const float* __restrict__ f_pre,
    float* __restrict__ a2_out, float* __restrict__ M2_out, float* __restrict__ nfl_out) {
  const int bh = blockIdx.x;
  const int tid = threadIdx.x;
  __shared__ float buf[256];
  const float* __restrict__ fp = f_pre + (size_t)bh * kS;
  const float* __restrict__ ip = i_pre + (size_t)bh * kS;
  float carry_cs = 0.f;
  float carry_max = -1e30f;
  for (int chunk = 0; chunk < kS / 256; ++chunk) {
    const int s = chunk * 256 + tid;
    const float f = fp[s];
    const float lf = fminf(f, 0.f) - log1pf(expf(-fabsf(f)));
    buf[tid] = lf;
    __syncthreads();
    for (int off = 1; off < 256; off <<= 1) {
      const float t = (tid >= off) ? buf[tid - off] : 0.f;
      __syncthreads();
      buf[tid] += t;
      __syncthreads();
    }
    const float cs = carry_cs + buf[tid];
    const float chunk_sum = buf[255];
    const float av = ip[s] - cs;
    __syncthreads();
    buf[tid] = av;
    __syncthreads();
    for (int off = 1; off < 256; off <<= 1) {
      const float t = (tid >= off) ? buf[tid - off] : -1e30f;
      __syncthreads();
      buf[tid] = fmaxf(buf[tid], t);
      __syncthreads();
    }
    const float Mv = fmaxf(carry_max, buf[tid]);
    const float chunk_max = buf[255];
    const size_t idx = (size_t)bh * kS + s;
    a2_out[idx]  = av * kLog2e;
    M2_out[idx]  = Mv * kLog2e;
    nfl_out[idx] = expf(-(cs + Mv));
    carry_cs += chunk_sum;
    carry_max = fmaxf(carry_max, chunk_max);
    __syncthreads();
  }
}

// ---------------- attn: MFMA, global_load_lds staging, H^T PV ----------------
__global__ __launch_bounds__(256, 4) void attn_mfma_kernel(
    const ushort* __restrict__ Qb, const ushort* __restrict__ Kb,
    const ushort* __restrict__ Vtb,
    const float* __restrict__ a2, const float* __restrict__ M2,
    const float* __restrict__ nfl, const float* __restrict__ nw,
    float* __restrict__ out) {
  const int bh = blockIdx.y;
  const int b = bh >> 3, h = bh & 7;
  const int it = (int)gridDim.x - 1 - (int)blockIdx.x;  // heavy blocks first
  const int tid = threadIdx.x;
  const int w = tid >> 6, lane = tid & 63;
  const int l15 = lane & 15, g = lane >> 4;
  const int row0 = it * BM;
  const int rowbase = row0 + w * 16;
  const size_t bhS = (size_t)bh * kS;

  __shared__ ushort Klds[BN * kDH];      // [j][d], 256B rows, chunk^=(j&7)
  __shared__ ushort Vlds[kDH * BN];      // [d][j], 128B rows, chunk^=(d&7)
  __shared__ ushort Plds[4][16 * BN];    // per-wave [i][j], 128B rows, chunk^=(i&7)

  const ushort* __restrict__ Qbh = Qb + bhS * 128;
  const char* __restrict__ KgBase = reinterpret_cast<const char*>(Kb + bhS * 128);
  const char* __restrict__ VgBase = reinterpret_cast<const char*>(Vtb + (size_t)bh * 128 * kS);

  // Q fragments (already bf16, pre-scaled)
  bf16x8 qf[4];
  {
    const ushort* qrow = Qbh + (size_t)(rowbase + l15) * 128;
#pragma unroll
    for (int ks = 0; ks < 4; ++ks)
      qf[ks] = *reinterpret_cast<const bf16x8*>(qrow + ks * 32 + g * 8);
  }
  float M2row[4];
#pragma unroll
  for (int reg = 0; reg < 4; ++reg) M2row[reg] = M2[bhS + rowbase + g * 4 + reg];

  // staging offsets (source XOR-pre-swizzled; LDS dest linear)
  int koffG[4], voffG[4];
#pragma unroll
  for (int i = 0; i < 4; ++i) {
    const int L = tid * 16 + i * 4096;
    { const int j = L >> 8, c = (L >> 4) & 15;
      koffG[i] = j * 256 + ((c ^ (j & 7)) << 4); }
    { const int d = L >> 7, c = (L >> 4) & 7;
      voffG[i] = d * 4096 + ((c ^ (d & 7)) << 4); }
  }

  f32x4 hacc[8];
#pragma unroll
  for (int db = 0; db < 8; ++db) hacc[db] = (f32x4){0.f, 0.f, 0.f, 0.f};
  float rs[4] = {0.f, 0.f, 0.f, 0.f};

  for (int jt = 0; jt <= it; ++jt) {
    __syncthreads();  // prev tile fully consumed
    const char* Kg = KgBase + (size_t)jt * 16384;
    const char* Vg = VgBase + (size_t)jt * 128;
#pragma unroll
    for (int i = 0; i < 4; ++i)
      gload16(Kg + koffG[i], reinterpret_cast<char*>(Klds) + tid * 16 + i * 4096);
#pragma unroll
    for (int i = 0; i < 4; ++i)
      gload16(Vg + voffG[i], reinterpret_cast<char*>(Vlds) + tid * 16 + i * 4096);
    float av[4];
#pragma unroll
    for (int cb = 0; cb < 4; ++cb) av[cb] = a2[bhS + jt * 64 + cb * 16 + l15];
    __syncthreads();  // staging visible (barrier drains vmcnt)

    // ---- QK^T: S tile 16 x 64 per wave ----
    f32x4 sacc[4];
#pragma unroll
    for (int cb = 0; cb < 4; ++cb) sacc[cb] = (f32x4){0.f, 0.f, 0.f, 0.f};
#pragma unroll
    for (int ks = 0; ks < 4; ++ks) {
#pragma unroll
      for (int cb = 0; cb < 4; ++cb) {
        const int j = cb * 16 + l15;
        const int kb = j * 256 + ((ks * 64 + g * 16) ^ ((l15 & 7) << 4));
        const bf16x8 kf = *reinterpret_cast<const bf16x8*>(
            reinterpret_cast<const char*>(Klds) + kb);
        sacc[cb] = __builtin_amdgcn_mfma_f32_16x16x32_bf16(qf[ks], kf, sacc[cb], 0, 0, 0);
      }
    }

    // ---- decay * mask -> rowsum, P -> bf16 LDS ----
#pragma unroll
    for (int cb = 0; cb < 4; ++cb) {
      const int jg = jt * 64 + cb * 16 + l15;
#pragma unroll
      for (int reg = 0; reg < 4; ++reg) {
        const int ig = rowbase + g * 4 + reg;
        float val = 0.f;
        if (jg <= ig) val = sacc[cb][reg] * exp2f(av[cb] - M2row[reg]);
        rs[reg] += val;
        const int r = g * 4 + reg;
        const int pb = r * 128 + ((cb * 32 + l15 * 2) ^ ((r & 7) << 4));
        *reinterpret_cast<ushort*>(
            reinterpret_cast<char*>(&Plds[w][0]) + pb) = f2bf(val);
      }
    }

    // ---- PV as H^T: hacc[db] (row=d, col=i) ----
#pragma unroll
    for (int ks2 = 0; ks2 < 2; ++ks2) {
      const int pbyte = l15 * 128 + ((ks2 * 64 + g * 16) ^ ((l15 & 7) << 4));
      const bf16x8 pf = *reinterpret_cast<const bf16x8*>(
          reinterpret_cast<const char*>(&Plds[w][0]) + pbyte);
#pragma unroll
      for (int db = 0; db < 8; ++db) {
        const int d = db * 16 + l15;
        const int vb = d * 128 + ((ks2 * 64 + g * 16) ^ ((d & 7) << 4));
        const bf16x8 vf = *reinterpret_cast<const bf16x8*>(
            reinterpret_cast<const char*>(Vlds) + vb);
        hacc[db] = __builtin_amdgcn_mfma_f32_16x16x32_bf16(vf, pf, hacc[db], 0, 0, 0);
      }
    }
  }

  // ---- epilogue ----
#pragma unroll
  for (int reg = 0; reg < 4; ++reg) {
    float x = rs[reg];
    x += __shfl_xor(x, 1); x += __shfl_xor(x, 2);
    x += __shfl_xor(x, 4); x += __shfl_xor(x, 8);
    rs[reg] = x;
  }
  float* rsp = reinterpret_cast<float*>(&Plds[w][0]);
  if (l15 == 0) {
#pragma unroll
    for (int reg = 0; reg < 4; ++reg) rsp[g * 4 + reg] = rs[reg];
  }
  const float rsum = rsp[l15];
  const float nf = nfl[bhS + rowbase + l15];
  const float inv = 1.f / (fmaxf(fabsf(rsum), nf) + 1e-6f);
  float ps = 0.f, pq = 0.f;
#pragma unroll
  for (int db = 0; db < 8; ++db) {
#pragma unroll
    for (int reg = 0; reg < 4; ++reg) {
      const float hv = hacc[db][reg] * inv;
      hacc[db][reg] = hv;
      ps += hv; pq += hv * hv;
    }
  }
  ps += __shfl_xor(ps, 16); ps += __shfl_xor(ps, 32);
  pq += __shfl_xor(pq, 16); pq += __shfl_xor(pq, 32);
  const float mu = ps * (1.f / 128.f);
  const float var = pq * (1.f / 128.f) - mu * mu;
  const float rstd = rsqrtf(var + 1e-5f);
  const int srow = rowbase + l15;
  float* __restrict__ orow = out + ((size_t)b * 2048 + srow) * 1024 + h * 128;
#pragma unroll
  for (int db = 0; db < 8; ++db) {
    const int d0 = db * 16 + g * 4;
    const float4 nw4 = *reinterpret_cast<const float4*>(nw + h * 128 + d0);
    float4 o;
    o.x = (hacc[db][0] - mu) * rstd * nw4.x;
    o.y = (hacc[db][1] - mu) * rstd * nw4.y;
    o.z = (hacc[db][2] - mu) * rstd * nw4.z;
    o.w = (hacc[db][3] - mu) * rstd * nw4.w;
    *reinterpret_cast<float4*>(orow + d0) = o;
  }
}

extern "C" void kernel_launch(void* const* d_in, const int* in_sizes, int n_in,
                              void* d_out, int out_size, void* d_ws, size_t ws_size,
                              hipStream_t stream) {
  const float* q  = (const float*)d_in[0];
  const float* k  = (const float*)d_in[1];
  const float* v  = (const float*)d_in[2];
  const float* iw = (const float*)d_in[3];
  const float* ib = (const float*)d_in[4];
  const float* fw = (const float*)d_in[5];
  const float* fb = (const float*)d_in[6];
  const float* nw = (const float*)d_in[7];
  float* out = (float*)d_out;

  char* ws = (char*)d_ws;
  const int BHS = kB * kNH * kS;                 // 32768
  float* i_pre = (float*)ws;
  float* f_pre = i_pre + BHS;
  float* a2    = i_pre + 2 * BHS;
  float* M2    = i_pre + 3 * BHS;
  float* nfl   = i_pre + 4 * BHS;
  char* ws2 = ws + (size_t)5 * BHS * 4;          // 655360 B
  ushort* Qb  = (ushort*)ws2;                    // 8 MB each
  ushort* Kb  = Qb + (size_t)kB * kNH * kS * kDH;
  ushort* Vtb = Kb + (size_t)kB * kNH * kS * kDH;

  convqk_kernel<<<dim3(2048), dim3(256), 0, stream>>>(q, k, Qb, Kb);
  convv_kernel<<<dim3(kB * kNH, kS / 256), dim3(256), 0, stream>>>(v, Vtb);
  gates_kernel<<<dim3(kB * kS / 4), dim3(256), 0, stream>>>(q, k, v, iw, ib, fw, fb,
                                                            i_pre, f_pre);
  scan_kernel<<<dim3(kB * kNH), dim3(256), 0, stream>>>(i_pre, f_pre, a2, M2, nfl);
  attn_mfma_kernel<<<dim3(kS / BM, kB * kNH), dim3(256), 0, stream>>>(
      Qb, Kb, Vtb, a2, M2, nfl, nw, out);
}

// Round 4
// 123.796 us; speedup vs baseline: 59.5909x; 1.2742x over previous
//
#include <hip/hip_runtime.h>
#include <hip/hip_bf16.h>
#include <math.h>

typedef __attribute__((ext_vector_type(8))) short bf16x8;
typedef __attribute__((ext_vector_type(4))) float f32x4;

namespace {
constexpr int kB = 2, kS = 2048, kE = 1024, kNH = 8, kDH = 128, kE3 = 3072;
constexpr float kLog2e = 1.4426950408889634f;
constexpr int BM = 64, BN = 64;
}

__device__ __forceinline__ ushort f2bf(float x) {
  union { __hip_bfloat16 b; ushort u; } c; c.b = __float2bfloat16(x); return c.u;
}
__device__ __forceinline__ uint pk2(float a, float b) {
  return (uint)f2bf(a) | ((uint)f2bf(b) << 16);
}
__device__ __forceinline__ void gload16(const void* g, void* l) {
  __builtin_amdgcn_global_load_lds(
      (const __attribute__((address_space(1))) void*)g,
      (__attribute__((address_space(3))) void*)l, 16, 0, 0);
}

__device__ __forceinline__ float butterfly64(float* acc, int lane) {
  int cur = 64;
#pragma unroll
  for (int lv = 0; lv < 6; ++lv) {
    const int bmask = 1 << lv;
    const int half = cur >> 1;
    const bool hi = (lane & bmask) != 0;
#pragma unroll
    for (int i = 0; i < 32; ++i) {
      if (i >= half) break;
      const float keep = hi ? acc[i + half] : acc[i];
      const float send = hi ? acc[i] : acc[i + half];
      acc[i] = keep + __shfl_xor(send, bmask);
    }
    cur = half;
  }
  return acc[0];
}

// ---------------- preproc: Kb bf16, Vtb bf16 transposed, gate pre-activations ----------------
__global__ __launch_bounds__(256, 1) void preproc_kernel(
    const float* __restrict__ q, const float* __restrict__ k, const float* __restrict__ v,
    const float* __restrict__ iw, const float* __restrict__ ib,
    const float* __restrict__ fw, const float* __restrict__ fb,
    ushort* __restrict__ Kb, ushort* __restrict__ Vtb,
    float* __restrict__ i_pre, float* __restrict__ f_pre) {
  const int b = blockIdx.y;
  const int s0 = blockIdx.x * 16;
  const int tid = threadIdx.x;
  const int w = tid >> 6, lane = tid & 63;
  __shared__ ushort Vst[16 * 1024];   // 32 KB, chunk-XOR-swizzled rows of 2048 B

  // ---- phase 1: convert K -> Kb, stage V -> LDS (wave w owns tokens w*4..w*4+3) ----
#pragma unroll
  for (int t = 0; t < 4; ++t) {
    const int tokl = w * 4 + t;
    const int s = s0 + tokl;
    const size_t base = ((size_t)b * kS + s) * kE + lane * 16;
    const float4 k0 = *reinterpret_cast<const float4*>(k + base);
    const float4 k1 = *reinterpret_cast<const float4*>(k + base + 4);
    const float4 k2 = *reinterpret_cast<const float4*>(k + base + 8);
    const float4 k3 = *reinterpret_cast<const float4*>(k + base + 12);
    uint4 pa, pb;
    pa.x = pk2(k0.x, k0.y); pa.y = pk2(k0.z, k0.w);
    pa.z = pk2(k1.x, k1.y); pa.w = pk2(k1.z, k1.w);
    pb.x = pk2(k2.x, k2.y); pb.y = pk2(k2.z, k2.w);
    pb.z = pk2(k3.x, k3.y); pb.w = pk2(k3.z, k3.w);
    ushort* kd = Kb + ((size_t)(b * 8 + (lane >> 3)) * kS + s) * 128 + (lane & 7) * 16;
    *reinterpret_cast<uint4*>(kd) = pa;
    *reinterpret_cast<uint4*>(kd + 8) = pb;

    const float4 v0 = *reinterpret_cast<const float4*>(v + base);
    const float4 v1 = *reinterpret_cast<const float4*>(v + base + 4);
    const float4 v2 = *reinterpret_cast<const float4*>(v + base + 8);
    const float4 v3 = *reinterpret_cast<const float4*>(v + base + 12);
    uint4 va, vb4;
    va.x = pk2(v0.x, v0.y); va.y = pk2(v0.z, v0.w);
    va.z = pk2(v1.x, v1.y); va.w = pk2(v1.z, v1.w);
    vb4.x = pk2(v2.x, v2.y); vb4.y = pk2(v2.z, v2.w);
    vb4.z = pk2(v3.x, v3.y); vb4.w = pk2(v3.z, v3.w);
    const int cc0 = lane * 2, cc1 = lane * 2 + 1;
    *reinterpret_cast<uint4*>(reinterpret_cast<char*>(Vst) + tokl * 2048 +
                              ((cc0 ^ ((cc0 >> 3) & 7)) << 4)) = va;
    *reinterpret_cast<uint4*>(reinterpret_cast<char*>(Vst) + tokl * 2048 +
                              ((cc1 ^ ((cc1 >> 3) & 7)) << 4)) = vb4;
  }
  __syncthreads();

  // ---- phase 2: transpose V out of LDS: Vtb[b][h][d][s] ----
#pragma unroll
  for (int j = 0; j < 4; ++j) {
    const int e = j * 256 + tid;          // h = e>>7, d = e&127
    const int cc = e >> 3;
    const int off = ((cc ^ ((cc >> 3) & 7)) << 4) + (e & 7) * 2;
    uint tmp[8];
#pragma unroll
    for (int t2 = 0; t2 < 16; t2 += 2) {
      const ushort u0 = *reinterpret_cast<const ushort*>(
          reinterpret_cast<const char*>(Vst) + t2 * 2048 + off);
      const ushort u1 = *reinterpret_cast<const ushort*>(
          reinterpret_cast<const char*>(Vst) + (t2 + 1) * 2048 + off);
      tmp[t2 >> 1] = (uint)u0 | ((uint)u1 << 16);
    }
    uint4 o0, o1;
    o0.x = tmp[0]; o0.y = tmp[1]; o0.z = tmp[2]; o0.w = tmp[3];
    o1.x = tmp[4]; o1.y = tmp[5]; o1.z = tmp[6]; o1.w = tmp[7];
    ushort* vd = Vtb + ((size_t)(b * 8 + (e >> 7)) * 128 + (e & 127)) * kS + s0;
    *reinterpret_cast<uint4*>(vd) = o0;
    *reinterpret_cast<uint4*>(vd + 8) = o1;
  }

  // ---- phase 3: gates, 2 groups of 8 tokens; waves split features ----
  float* red = reinterpret_cast<float*>(Vst);   // alias (phase-2 reads done after barrier)
  for (int tg = 0; tg < 2; ++tg) {
    float acc[128];
#pragma unroll
    for (int i = 0; i < 128; ++i) acc[i] = 0.f;
    for (int step = 0; step < 12; ++step) {
      const int ebase = w * 768 + step * 64;
      const int seg = ebase >> 10;
      const int eo = (ebase & 1023) + lane;
      const int e = ebase + lane;
      const float* __restrict__ src = (seg == 0) ? q : (seg == 1) ? k : v;
      float gv[8];
#pragma unroll
      for (int t = 0; t < 8; ++t)
        gv[t] = src[((size_t)b * kS + s0 + tg * 8 + t) * kE + eo];
      float wi[8], wf[8];
#pragma unroll
      for (int h = 0; h < 8; ++h) {
        wi[h] = iw[h * kE3 + e];
        wf[h] = fw[h * kE3 + e];
      }
#pragma unroll
      for (int t = 0; t < 8; ++t) {
#pragma unroll
        for (int h = 0; h < 8; ++h) {
          acc[t * 16 + h]     += gv[t] * wi[h];
          acc[t * 16 + 8 + h] += gv[t] * wf[h];
        }
      }
    }
    const float r0 = butterfly64(acc, lane);
    const float r1 = butterfly64(acc + 64, lane);
    const int a = ((lane & 1) << 5) | ((lane & 2) << 3) | ((lane & 4) << 1) |
                  ((lane & 8) >> 1) | ((lane & 16) >> 3) | ((lane & 32) >> 5);
    __syncthreads();                 // red region free (phase2 / prev tg done)
    red[w * 128 + a] = r0;
    red[w * 128 + 64 + a] = r1;
    __syncthreads();
    if (tid < 128) {
      const float val = red[tid] + red[128 + tid] + red[256 + tid] + red[384 + tid];
      const int tok_lo = tid >> 4, gate = tid & 15, h = gate & 7;
      const int token = s0 + tg * 8 + tok_lo;
      const size_t idx = ((size_t)(b * 8 + h)) * kS + token;
      if (gate < 8) i_pre[idx] = val + ib[h];
      else          f_pre[idx] = val + fb[h];
    }
  }
}

// ---------------- scan: shfl-based; outputs a2, M2 (log2-scaled), nfl ----------------
__global__ __launch_bounds__(256) void scan_kernel(
    const float* __restrict__ i_pre, const float* __restrict__ f_pre,
    float* __restrict__ a2_out, float* __restrict__ M2_out, float* __restrict__ nfl_out) {
  const int bh = blockIdx.x;
  const int tid = threadIdx.x;
  const int w = tid >> 6, lane = tid & 63;
  __shared__ float wsum[4], wmax[4];
  const float* __restrict__ fp = f_pre + (size_t)bh * kS;
  const float* __restrict__ ip = i_pre + (size_t)bh * kS;
  const int s0 = tid * 8;

  const float4 fa = *reinterpret_cast<const float4*>(fp + s0);
  const float4 fb4 = *reinterpret_cast<const float4*>(fp + s0 + 4);
  float lf[8];
  {
    const float fv[8] = {fa.x, fa.y, fa.z, fa.w, fb4.x, fb4.y, fb4.z, fb4.w};
#pragma unroll
    for (int j = 0; j < 8; ++j)
      lf[j] = fminf(fv[j], 0.f) - log1pf(expf(-fabsf(fv[j])));
  }
  float run = 0.f, pcs[8];
#pragma unroll
  for (int j = 0; j < 8; ++j) { run += lf[j]; pcs[j] = run; }
  float x = run;
#pragma unroll
  for (int d = 1; d < 64; d <<= 1) {
    const float t = __shfl_up(x, d);
    if (lane >= d) x += t;
  }
  if (lane == 63) wsum[w] = x;
  __syncthreads();
  float woff = 0.f;
#pragma unroll
  for (int i = 0; i < 4; ++i) if (i < w) woff += wsum[i];
  const float csbase = woff + x - run;
  float cs[8];
#pragma unroll
  for (int j = 0; j < 8; ++j) cs[j] = csbase + pcs[j];

  const float4 ia = *reinterpret_cast<const float4*>(ip + s0);
  const float4 ib4 = *reinterpret_cast<const float4*>(ip + s0 + 4);
  float av[8];
  {
    const float iv[8] = {ia.x, ia.y, ia.z, ia.w, ib4.x, ib4.y, ib4.z, ib4.w};
#pragma unroll
    for (int j = 0; j < 8; ++j) av[j] = iv[j] - cs[j];
  }
  float rmax = -1e30f, pm[8];
#pragma unroll
  for (int j = 0; j < 8; ++j) { rmax = fmaxf(rmax, av[j]); pm[j] = rmax; }
  float mi = rmax;
#pragma unroll
  for (int d = 1; d < 64; d <<= 1) {
    const float t = __shfl_up(mi, d);
    if (lane >= d) mi = fmaxf(mi, t);
  }
  if (lane == 63) wmax[w] = mi;
  float mexcl = __shfl_up(mi, 1);
  if (lane == 0) mexcl = -1e30f;
  __syncthreads();
  float wmoff = -1e30f;
#pragma unroll
  for (int i = 0; i < 4; ++i) if (i < w) wmoff = fmaxf(wmoff, wmax[i]);
  const float mbase = fmaxf(wmoff, mexcl);

  float4 a2lo, a2hi, m2lo, m2hi, nflo, nfhi;
  float M[8];
#pragma unroll
  for (int j = 0; j < 8; ++j) M[j] = fmaxf(mbase, pm[j]);
  a2lo.x = av[0] * kLog2e; a2lo.y = av[1] * kLog2e; a2lo.z = av[2] * kLog2e; a2lo.w = av[3] * kLog2e;
  a2hi.x = av[4] * kLog2e; a2hi.y = av[5] * kLog2e; a2hi.z = av[6] * kLog2e; a2hi.w = av[7] * kLog2e;
  m2lo.x = M[0] * kLog2e; m2lo.y = M[1] * kLog2e; m2lo.z = M[2] * kLog2e; m2lo.w = M[3] * kLog2e;
  m2hi.x = M[4] * kLog2e; m2hi.y = M[5] * kLog2e; m2hi.z = M[6] * kLog2e; m2hi.w = M[7] * kLog2e;
  nflo.x = expf(-(cs[0] + M[0])); nflo.y = expf(-(cs[1] + M[1]));
  nflo.z = expf(-(cs[2] + M[2])); nflo.w = expf(-(cs[3] + M[3]));
  nfhi.x = expf(-(cs[4] + M[4])); nfhi.y = expf(-(cs[5] + M[5]));
  nfhi.z = expf(-(cs[6] + M[6])); nfhi.w = expf(-(cs[7] + M[7]));
  const size_t o = (size_t)bh * kS + s0;
  *reinterpret_cast<float4*>(a2_out + o) = a2lo;
  *reinterpret_cast<float4*>(a2_out + o + 4) = a2hi;
  *reinterpret_cast<float4*>(M2_out + o) = m2lo;
  *reinterpret_cast<float4*>(M2_out + o + 4) = m2hi;
  *reinterpret_cast<float4*>(nfl_out + o) = nflo;
  *reinterpret_cast<float4*>(nfl_out + o + 4) = nfhi;
}

// ---------------- attn: MFMA + double-buffered global_load_lds staging ----------------
__global__ __launch_bounds__(256, 2) void attn_mfma_kernel(
    const float* __restrict__ qg, const ushort* __restrict__ Kb,
    const ushort* __restrict__ Vtb,
    const float* __restrict__ a2, const float* __restrict__ M2,
    const float* __restrict__ nfl, const float* __restrict__ nw,
    float* __restrict__ out) {
  const int bh = blockIdx.y;
  const int b = bh >> 3, h = bh & 7;
  const int it = (int)gridDim.x - 1 - (int)blockIdx.x;  // heavy blocks first
  const int tid = threadIdx.x;
  const int w = tid >> 6, lane = tid & 63;
  const int l15 = lane & 15, g = lane >> 4;
  const int row0 = it * BM;
  const int rowbase = row0 + w * 16;
  const size_t bhS = (size_t)bh * kS;

  __shared__ ushort Klds[2 * BN * kDH];   // 2 x 16 KB
  __shared__ ushort Vlds[2 * kDH * BN];   // 2 x 16 KB
  __shared__ ushort Plds[4][16 * BN];     // 8 KB

  const char* __restrict__ KgBase = reinterpret_cast<const char*>(Kb + bhS * 128);
  const char* __restrict__ VgBase = reinterpret_cast<const char*>(Vtb + (size_t)bh * 128 * kS);

  // Q fragments from f32 q, packed+scaled once
  bf16x8 qf[4];
  {
    const float scale = 0.08838834764831845f;
    const float* qrow = qg + ((size_t)b * kS + rowbase + l15) * kE + h * kDH;
#pragma unroll
    for (int ks = 0; ks < 4; ++ks) {
      const float4 lo = *reinterpret_cast<const float4*>(qrow + ks * 32 + g * 8);
      const float4 hi = *reinterpret_cast<const float4*>(qrow + ks * 32 + g * 8 + 4);
      bf16x8 f;
      f[0] = (short)f2bf(lo.x * scale); f[1] = (short)f2bf(lo.y * scale);
      f[2] = (short)f2bf(lo.z * scale); f[3] = (short)f2bf(lo.w * scale);
      f[4] = (short)f2bf(hi.x * scale); f[5] = (short)f2bf(hi.y * scale);
      f[6] = (short)f2bf(hi.z * scale); f[7] = (short)f2bf(hi.w * scale);
      qf[ks] = f;
    }
  }
  float M2row[4];
#pragma unroll
  for (int reg = 0; reg < 4; ++reg) M2row[reg] = M2[bhS + rowbase + g * 4 + reg];

  // pre-swizzled source offsets (LDS dest linear)
  int koffG[4], voffG[4];
#pragma unroll
  for (int i = 0; i < 4; ++i) {
    const int L = tid * 16 + i * 4096;
    { const int j = L >> 8, c = (L >> 4) & 15;
      koffG[i] = j * 256 + ((c ^ (j & 7)) << 4); }
    { const int d = L >> 7, c = (L >> 4) & 7;
      voffG[i] = d * 4096 + ((c ^ (d & 7)) << 4); }
  }

  auto stage = [&](int buf, int jt) {
    const char* Kg = KgBase + (size_t)jt * 16384;
    const char* Vg = VgBase + (size_t)jt * 128;
    char* kl = reinterpret_cast<char*>(Klds) + buf * 16384 + tid * 16;
    char* vl = reinterpret_cast<char*>(Vlds) + buf * 16384 + tid * 16;
#pragma unroll
    for (int i = 0; i < 4; ++i) gload16(Kg + koffG[i], kl + i * 4096);
#pragma unroll
    for (int i = 0; i < 4; ++i) gload16(Vg + voffG[i], vl + i * 4096);
  };

  f32x4 hacc[8];
#pragma unroll
  for (int db = 0; db < 8; ++db) hacc[db] = (f32x4){0.f, 0.f, 0.f, 0.f};
  float rs[4] = {0.f, 0.f, 0.f, 0.f};

  float avc[4];
#pragma unroll
  for (int cb = 0; cb < 4; ++cb) avc[cb] = a2[bhS + cb * 16 + l15];
  stage(0, 0);
  __syncthreads();

  for (int jt = 0; jt <= it; ++jt) {
    const int cur = jt & 1;
    float avn[4];
    if (jt < it) {
      stage(cur ^ 1, jt + 1);   // issue next tile early; latency hides under compute
#pragma unroll
      for (int cb = 0; cb < 4; ++cb)
        avn[cb] = a2[bhS + (jt + 1) * 64 + cb * 16 + l15];
    }

    // ---- QK^T: 16 x 64 S-tile per wave ----
    const int kbase = cur * 16384;
    f32x4 sacc[4];
#pragma unroll
    for (int cb = 0; cb < 4; ++cb) sacc[cb] = (f32x4){0.f, 0.f, 0.f, 0.f};
#pragma unroll
    for (int ks = 0; ks < 4; ++ks) {
#pragma unroll
      for (int cb = 0; cb < 4; ++cb) {
        const int j = cb * 16 + l15;
        const int kb = kbase + j * 256 + ((ks * 64 + g * 16) ^ ((l15 & 7) << 4));
        const bf16x8 kf = *reinterpret_cast<const bf16x8*>(
            reinterpret_cast<const char*>(Klds) + kb);
        sacc[cb] = __builtin_amdgcn_mfma_f32_16x16x32_bf16(qf[ks], kf, sacc[cb], 0, 0, 0);
      }
    }

    // ---- decay * mask -> rowsum, P -> bf16 LDS ----
#pragma unroll
    for (int cb = 0; cb < 4; ++cb) {
      const int jg = jt * 64 + cb * 16 + l15;
#pragma unroll
      for (int reg = 0; reg < 4; ++reg) {
        const int ig = rowbase + g * 4 + reg;
        float val = 0.f;
        if (jg <= ig) val = sacc[cb][reg] * exp2f(avc[cb] - M2row[reg]);
        rs[reg] += val;
        const int r = g * 4 + reg;
        const int pb = r * 128 + ((cb * 32 + l15 * 2) ^ ((r & 7) << 4));
        *reinterpret_cast<ushort*>(
            reinterpret_cast<char*>(&Plds[w][0]) + pb) = f2bf(val);
      }
    }

    // ---- PV as H^T ----
    const int vbase = cur * 16384;
#pragma unroll
    for (int ks2 = 0; ks2 < 2; ++ks2) {
      const int pbyte = l15 * 128 + ((ks2 * 64 + g * 16) ^ ((l15 & 7) << 4));
      const bf16x8 pf = *reinterpret_cast<const bf16x8*>(
          reinterpret_cast<const char*>(&Plds[w][0]) + pbyte);
#pragma unroll
      for (int db = 0; db < 8; ++db) {
        const int d = db * 16 + l15;
        const int vb = vbase + d * 128 + ((ks2 * 64 + g * 16) ^ ((d & 7) << 4));
        const bf16x8 vf = *reinterpret_cast<const bf16x8*>(
            reinterpret_cast<const char*>(Vlds) + vb);
        hacc[db] = __builtin_amdgcn_mfma_f32_16x16x32_bf16(vf, pf, hacc[db], 0, 0, 0);
      }
    }
    __syncthreads();   // drains staging vmcnt; next iter's buffer ready
    if (jt < it) {
#pragma unroll
      for (int cb = 0; cb < 4; ++cb) avc[cb] = avn[cb];
    }
  }

  // ---- epilogue ----
#pragma unroll
  for (int reg = 0; reg < 4; ++reg) {
    float x = rs[reg];
    x += __shfl_xor(x, 1); x += __shfl_xor(x, 2);
    x += __shfl_xor(x, 4); x += __shfl_xor(x, 8);
    rs[reg] = x;
  }
  float* rsp = reinterpret_cast<float*>(&Plds[w][0]);
  if (l15 == 0) {
#pragma unroll
    for (int reg = 0; reg < 4; ++reg) rsp[g * 4 + reg] = rs[reg];
  }
  const float rsum = rsp[l15];
  const float nf = nfl[bhS + rowbase + l15];
  const float inv = 1.f / (fmaxf(fabsf(rsum), nf) + 1e-6f);
  float ps = 0.f, pq = 0.f;
#pragma unroll
  for (int db = 0; db < 8; ++db) {
#pragma unroll
    for (int reg = 0; reg < 4; ++reg) {
      const float hv = hacc[db][reg] * inv;
      hacc[db][reg] = hv;
      ps += hv; pq += hv * hv;
    }
  }
  ps += __shfl_xor(ps, 16); ps += __shfl_xor(ps, 32);
  pq += __shfl_xor(pq, 16); pq += __shfl_xor(pq, 32);
  const float mu = ps * (1.f / 128.f);
  const float var = pq * (1.f / 128.f) - mu * mu;
  const float rstd = rsqrtf(var + 1e-5f);
  const int srow = rowbase + l15;
  float* __restrict__ orow = out + ((size_t)b * kS + srow) * kE + h * kDH;
#pragma unroll
  for (int db = 0; db < 8; ++db) {
    const int d0 = db * 16 + g * 4;
    const float4 nw4 = *reinterpret_cast<const float4*>(nw + h * kDH + d0);
    float4 o;
    o.x = (hacc[db][0] - mu) * rstd * nw4.x;
    o.y = (hacc[db][1] - mu) * rstd * nw4.y;
    o.z = (hacc[db][2] - mu) * rstd * nw4.z;
    o.w = (hacc[db][3] - mu) * rstd * nw4.w;
    *reinterpret_cast<float4*>(orow + d0) = o;
  }
}

extern "C" void kernel_launch(void* const* d_in, const int* in_sizes, int n_in,
                              void* d_out, int out_size, void* d_ws, size_t ws_size,
                              hipStream_t stream) {
  const float* q  = (const float*)d_in[0];
  const float* k  = (const float*)d_in[1];
  const float* v  = (const float*)d_in[2];
  const float* iw = (const float*)d_in[3];
  const float* ib = (const float*)d_in[4];
  const float* fw = (const float*)d_in[5];
  const float* fb = (const float*)d_in[6];
  const float* nw = (const float*)d_in[7];
  float* out = (float*)d_out;

  char* ws = (char*)d_ws;
  const int BHS = kB * kNH * kS;                 // 32768
  float* i_pre = (float*)ws;
  float* f_pre = i_pre + BHS;
  float* a2    = i_pre + 2 * BHS;
  float* M2    = i_pre + 3 * BHS;
  float* nfl   = i_pre + 4 * BHS;
  char* ws2 = ws + (size_t)5 * BHS * 4;          // 655360 B
  ushort* Kb  = (ushort*)ws2;                    // 8.4 MB
  ushort* Vtb = Kb + (size_t)kB * kNH * kS * kDH;

  preproc_kernel<<<dim3(kS / 16, kB), dim3(256), 0, stream>>>(
      q, k, v, iw, ib, fw, fb, Kb, Vtb, i_pre, f_pre);
  scan_kernel<<<dim3(kB * kNH), dim3(256), 0, stream>>>(i_pre, f_pre, a2, M2, nfl);
  attn_mfma_kernel<<<dim3(kS / BM, kB * kNH), dim3(256), 0, stream>>>(
      q, Kb, Vtb, a2, M2, nfl, nw, out);
}

// Round 5
// 122.391 us; speedup vs baseline: 60.2749x; 1.0115x over previous
//
#include <hip/hip_runtime.h>
#include <hip/hip_bf16.h>
#include <math.h>

typedef __attribute__((ext_vector_type(8))) short bf16x8;
typedef __attribute__((ext_vector_type(4))) float f32x4;

namespace {
constexpr int kB = 2, kS = 2048, kE = 1024, kNH = 8, kDH = 128, kE3 = 3072;
constexpr float kLog2e = 1.4426950408889634f;
constexpr int BM = 64, BN = 64;
constexpr int kHeavy = 16;          // tiles it>=16 are split into 2 chunks
constexpr int kUnits = 16 + 2 * 16; // 48 work units per bh
}

__device__ __forceinline__ ushort f2bf(float x) {
  union { __hip_bfloat16 b; ushort u; } c; c.b = __float2bfloat16(x); return c.u;
}
__device__ __forceinline__ uint pk2(float a, float b) {
  return (uint)f2bf(a) | ((uint)f2bf(b) << 16);
}
__device__ __forceinline__ void gload16(const void* g, void* l) {
  __builtin_amdgcn_global_load_lds(
      (const __attribute__((address_space(1))) void*)g,
      (__attribute__((address_space(3))) void*)l, 16, 0, 0);
}

__device__ __forceinline__ float butterfly64(float* acc, int lane) {
  int cur = 64;
#pragma unroll
  for (int lv = 0; lv < 6; ++lv) {
    const int bmask = 1 << lv;
    const int half = cur >> 1;
    const bool hi = (lane & bmask) != 0;
#pragma unroll
    for (int i = 0; i < 32; ++i) {
      if (i >= half) break;
      const float keep = hi ? acc[i + half] : acc[i];
      const float send = hi ? acc[i] : acc[i + half];
      acc[i] = keep + __shfl_xor(send, bmask);
    }
    cur = half;
  }
  return acc[0];
}

// ---------------- convkv: Kb bf16 head-major + Vtb bf16 transposed ----------------
__global__ __launch_bounds__(256) void convkv_kernel(
    const float* __restrict__ k, const float* __restrict__ v,
    ushort* __restrict__ Kb, ushort* __restrict__ Vtb) {
  const int b = blockIdx.y;
  const int s0 = blockIdx.x * 8;
  const int tid = threadIdx.x;
  const int w = tid >> 6, lane = tid & 63;
  __shared__ ushort Vst[8 * 1024];   // 16 KB, token rows of 2048 B, chunk-XOR swizzle

  // phase 1: wave w owns tokens w*2, w*2+1; lane covers 16 contiguous e
#pragma unroll
  for (int t = 0; t < 2; ++t) {
    const int tokl = w * 2 + t;
    const int s = s0 + tokl;
    const size_t base = ((size_t)b * kS + s) * kE + lane * 16;
    const float4 k0 = *reinterpret_cast<const float4*>(k + base);
    const float4 k1 = *reinterpret_cast<const float4*>(k + base + 4);
    const float4 k2 = *reinterpret_cast<const float4*>(k + base + 8);
    const float4 k3 = *reinterpret_cast<const float4*>(k + base + 12);
    uint4 pa, pb;
    pa.x = pk2(k0.x, k0.y); pa.y = pk2(k0.z, k0.w);
    pa.z = pk2(k1.x, k1.y); pa.w = pk2(k1.z, k1.w);
    pb.x = pk2(k2.x, k2.y); pb.y = pk2(k2.z, k2.w);
    pb.z = pk2(k3.x, k3.y); pb.w = pk2(k3.z, k3.w);
    ushort* kd = Kb + ((size_t)(b * 8 + (lane >> 3)) * kS + s) * 128 + (lane & 7) * 16;
    *reinterpret_cast<uint4*>(kd) = pa;
    *reinterpret_cast<uint4*>(kd + 8) = pb;

    const float4 v0 = *reinterpret_cast<const float4*>(v + base);
    const float4 v1 = *reinterpret_cast<const float4*>(v + base + 4);
    const float4 v2 = *reinterpret_cast<const float4*>(v + base + 8);
    const float4 v3 = *reinterpret_cast<const float4*>(v + base + 12);
    uint4 va, vb4;
    va.x = pk2(v0.x, v0.y); va.y = pk2(v0.z, v0.w);
    va.z = pk2(v1.x, v1.y); va.w = pk2(v1.z, v1.w);
    vb4.x = pk2(v2.x, v2.y); vb4.y = pk2(v2.z, v2.w);
    vb4.z = pk2(v3.x, v3.y); vb4.w = pk2(v3.z, v3.w);
    const int cc0 = lane * 2, cc1 = lane * 2 + 1;
    *reinterpret_cast<uint4*>(reinterpret_cast<char*>(Vst) + tokl * 2048 +
                              ((cc0 ^ ((cc0 >> 3) & 7)) << 4)) = va;
    *reinterpret_cast<uint4*>(reinterpret_cast<char*>(Vst) + tokl * 2048 +
                              ((cc1 ^ ((cc1 >> 3) & 7)) << 4)) = vb4;
  }
  __syncthreads();

  // phase 2: per e, gather the 8 tokens -> one uint4 to Vtb[b][h][d][s0..s0+8]
#pragma unroll
  for (int j = 0; j < 4; ++j) {
    const int e = j * 256 + tid;
    const int cc = e >> 3;
    const int off = ((cc ^ ((cc >> 3) & 7)) << 4) + (e & 7) * 2;
    uint tmp[4];
#pragma unroll
    for (int t2 = 0; t2 < 8; t2 += 2) {
      const ushort u0 = *reinterpret_cast<const ushort*>(
          reinterpret_cast<const char*>(Vst) + t2 * 2048 + off);
      const ushort u1 = *reinterpret_cast<const ushort*>(
          reinterpret_cast<const char*>(Vst) + (t2 + 1) * 2048 + off);
      tmp[t2 >> 1] = (uint)u0 | ((uint)u1 << 16);
    }
    uint4 o; o.x = tmp[0]; o.y = tmp[1]; o.z = tmp[2]; o.w = tmp[3];
    ushort* vd = Vtb + ((size_t)(b * 8 + (e >> 7)) * 128 + (e & 127)) * kS + s0;
    *reinterpret_cast<uint4*>(vd) = o;
  }
}

// ---------------- gates: 8 tokens/block; waves split (gate-half x K-half) ----------------
__global__ __launch_bounds__(256) void gates_kernel(
    const float* __restrict__ q, const float* __restrict__ k, const float* __restrict__ v,
    const float* __restrict__ iw, const float* __restrict__ ib,
    const float* __restrict__ fw, const float* __restrict__ fb,
    float* __restrict__ i_pre, float* __restrict__ f_pre) {
  const int tid = threadIdx.x;
  const int w = tid >> 6, lane = tid & 63;
  const int tokbase = blockIdx.x * 8;
  const int kh = w >> 1, gh = w & 1;
  const float* __restrict__ W = gh ? fw : iw;

  float acc[64];   // acc[t*8 + h]
#pragma unroll
  for (int i = 0; i < 64; ++i) acc[i] = 0.f;

  for (int step = 0; step < 24; ++step) {
    const int e = kh * 1536 + step * 64 + lane;
    const int seg = e >> 10;
    const int eo = e & 1023;
    const float* __restrict__ src = (seg == 0) ? q : (seg == 1) ? k : v;
    float gv[8];
#pragma unroll
    for (int t = 0; t < 8; ++t)
      gv[t] = src[(size_t)(tokbase + t) * kE + eo];
    float w8[8];
#pragma unroll
    for (int hh = 0; hh < 8; ++hh) w8[hh] = W[hh * kE3 + e];
#pragma unroll
    for (int t = 0; t < 8; ++t)
#pragma unroll
      for (int hh = 0; hh < 8; ++hh)
        acc[t * 8 + hh] += gv[t] * w8[hh];
  }
  const float r = butterfly64(acc, lane);
  const int a = ((lane & 1) << 5) | ((lane & 2) << 3) | ((lane & 4) << 1) |
                ((lane & 8) >> 1) | ((lane & 16) >> 3) | ((lane & 32) >> 5);
  __shared__ float red[4][64];
  red[w][a] = r;
  __syncthreads();
  if (tid < 128) {
    const int t = tid >> 4, g16 = tid & 15, hh = g16 & 7;
    const float val = (g16 < 8) ? red[0][t * 8 + hh] + red[2][t * 8 + hh]
                                : red[1][t * 8 + hh] + red[3][t * 8 + hh];
    const int token = tokbase + t;
    const int b = token >> 11, s = token & 2047;
    const size_t idx = ((size_t)(b * 8 + hh)) * kS + s;
    if (g16 < 8) i_pre[idx] = val + ib[hh];
    else         f_pre[idx] = val + fb[hh];
  }
}

// ---------------- scan: shfl-based; outputs a2, M2 (log2-scaled), nfl ----------------
__global__ __launch_bounds__(256) void scan_kernel(
    const float* __restrict__ i_pre, const float* __restrict__ f_pre,
    float* __restrict__ a2_out, float* __restrict__ M2_out, float* __restrict__ nfl_out) {
  const int bh = blockIdx.x;
  const int tid = threadIdx.x;
  const int w = tid >> 6, lane = tid & 63;
  __shared__ float wsum[4], wmax[4];
  const float* __restrict__ fp = f_pre + (size_t)bh * kS;
  const float* __restrict__ ip = i_pre + (size_t)bh * kS;
  const int s0 = tid * 8;

  const float4 fa = *reinterpret_cast<const float4*>(fp + s0);
  const float4 fb4 = *reinterpret_cast<const float4*>(fp + s0 + 4);
  float lf[8];
  {
    const float fv[8] = {fa.x, fa.y, fa.z, fa.w, fb4.x, fb4.y, fb4.z, fb4.w};
#pragma unroll
    for (int j = 0; j < 8; ++j)
      lf[j] = fminf(fv[j], 0.f) - log1pf(expf(-fabsf(fv[j])));
  }
  float run = 0.f, pcs[8];
#pragma unroll
  for (int j = 0; j < 8; ++j) { run += lf[j]; pcs[j] = run; }
  float x = run;
#pragma unroll
  for (int d = 1; d < 64; d <<= 1) {
    const float t = __shfl_up(x, d);
    if (lane >= d) x += t;
  }
  if (lane == 63) wsum[w] = x;
  __syncthreads();
  float woff = 0.f;
#pragma unroll
  for (int i = 0; i < 4; ++i) if (i < w) woff += wsum[i];
  const float csbase = woff + x - run;
  float cs[8];
#pragma unroll
  for (int j = 0; j < 8; ++j) cs[j] = csbase + pcs[j];

  const float4 ia = *reinterpret_cast<const float4*>(ip + s0);
  const float4 ib4 = *reinterpret_cast<const float4*>(ip + s0 + 4);
  float av[8];
  {
    const float iv[8] = {ia.x, ia.y, ia.z, ia.w, ib4.x, ib4.y, ib4.z, ib4.w};
#pragma unroll
    for (int j = 0; j < 8; ++j) av[j] = iv[j] - cs[j];
  }
  float rmax = -1e30f, pm[8];
#pragma unroll
  for (int j = 0; j < 8; ++j) { rmax = fmaxf(rmax, av[j]); pm[j] = rmax; }
  float mi = rmax;
#pragma unroll
  for (int d = 1; d < 64; d <<= 1) {
    const float t = __shfl_up(mi, d);
    if (lane >= d) mi = fmaxf(mi, t);
  }
  if (lane == 63) wmax[w] = mi;
  float mexcl = __shfl_up(mi, 1);
  if (lane == 0) mexcl = -1e30f;
  __syncthreads();
  float wmoff = -1e30f;
#pragma unroll
  for (int i = 0; i < 4; ++i) if (i < w) wmoff = fmaxf(wmoff, wmax[i]);
  const float mbase = fmaxf(wmoff, mexcl);

  float M[8];
#pragma unroll
  for (int j = 0; j < 8; ++j) M[j] = fmaxf(mbase, pm[j]);
  float4 a2lo, a2hi, m2lo, m2hi, nflo, nfhi;
  a2lo.x = av[0] * kLog2e; a2lo.y = av[1] * kLog2e; a2lo.z = av[2] * kLog2e; a2lo.w = av[3] * kLog2e;
  a2hi.x = av[4] * kLog2e; a2hi.y = av[5] * kLog2e; a2hi.z = av[6] * kLog2e; a2hi.w = av[7] * kLog2e;
  m2lo.x = M[0] * kLog2e; m2lo.y = M[1] * kLog2e; m2lo.z = M[2] * kLog2e; m2lo.w = M[3] * kLog2e;
  m2hi.x = M[4] * kLog2e; m2hi.y = M[5] * kLog2e; m2hi.z = M[6] * kLog2e; m2hi.w = M[7] * kLog2e;
  nflo.x = expf(-(cs[0] + M[0])); nflo.y = expf(-(cs[1] + M[1]));
  nflo.z = expf(-(cs[2] + M[2])); nflo.w = expf(-(cs[3] + M[3]));
  nfhi.x = expf(-(cs[4] + M[4])); nfhi.y = expf(-(cs[5] + M[5]));
  nfhi.z = expf(-(cs[6] + M[6])); nfhi.w = expf(-(cs[7] + M[7]));
  const size_t o = (size_t)bh * kS + s0;
  *reinterpret_cast<float4*>(a2_out + o) = a2lo;
  *reinterpret_cast<float4*>(a2_out + o + 4) = a2hi;
  *reinterpret_cast<float4*>(M2_out + o) = m2lo;
  *reinterpret_cast<float4*>(M2_out + o + 4) = m2hi;
  *reinterpret_cast<float4*>(nfl_out + o) = nflo;
  *reinterpret_cast<float4*>(nfl_out + o + 4) = nfhi;
}

// ---------------- shared epilogue: normalize + groupnorm + store ----------------
__device__ __forceinline__ void epilogue_store(
    f32x4* hacc, float rsum, float nf, int b, int h, int srow, int g,
    const float* __restrict__ nw, float* __restrict__ out) {
  const float inv = 1.f / (fmaxf(fabsf(rsum), nf) + 1e-6f);
  float ps = 0.f, pq = 0.f;
#pragma unroll
  for (int db = 0; db < 8; ++db) {
#pragma unroll
    for (int reg = 0; reg < 4; ++reg) {
      const float hv = hacc[db][reg] * inv;
      hacc[db][reg] = hv;
      ps += hv; pq += hv * hv;
    }
  }
  ps += __shfl_xor(ps, 16); ps += __shfl_xor(ps, 32);
  pq += __shfl_xor(pq, 16); pq += __shfl_xor(pq, 32);
  const float mu = ps * (1.f / 128.f);
  const float var = pq * (1.f / 128.f) - mu * mu;
  const float rstd = rsqrtf(var + 1e-5f);
  float* __restrict__ orow = out + ((size_t)b * kS + srow) * kE + h * kDH;
#pragma unroll
  for (int db = 0; db < 8; ++db) {
    const int d0 = db * 16 + g * 4;
    const float4 nw4 = *reinterpret_cast<const float4*>(nw + h * kDH + d0);
    float4 o;
    o.x = (hacc[db][0] - mu) * rstd * nw4.x;
    o.y = (hacc[db][1] - mu) * rstd * nw4.y;
    o.z = (hacc[db][2] - mu) * rstd * nw4.z;
    o.w = (hacc[db][3] - mu) * rstd * nw4.w;
    *reinterpret_cast<float4*>(orow + d0) = o;
  }
}

// ---------------- attn: MFMA, double-buffered, split heavy tiles ----------------
__global__ __launch_bounds__(256, 2) void attn_mfma_kernel(
    const float* __restrict__ qg, const ushort* __restrict__ Kb,
    const ushort* __restrict__ Vtb,
    const float* __restrict__ a2, const float* __restrict__ M2,
    const float* __restrict__ nfl, const float* __restrict__ nw,
    float* __restrict__ out, float* __restrict__ ph, float* __restrict__ prs) {
  const int bh = blockIdx.y;
  const int b = bh >> 3, h = bh & 7;
  const int u = kUnits - 1 - (int)blockIdx.x;   // heavy units dispatch first
  int it, j0, j1, chunk = -1;
  if (u < kHeavy) { it = u; j0 = 0; j1 = it; }
  else {
    const int t = (u - kHeavy) >> 1, c = (u - kHeavy) & 1;
    it = kHeavy + t;
    const int m = (it + 1) >> 1;
    if (c == 0) { j0 = 0; j1 = m - 1; } else { j0 = m; j1 = it; }
    chunk = ((bh * 16) + t) * 2 + c;
  }
  const int tid = threadIdx.x;
  const int w = tid >> 6, lane = tid & 63;
  const int l15 = lane & 15, g = lane >> 4;
  const int row0 = it * BM;
  const int rowbase = row0 + w * 16;
  const size_t bhS = (size_t)bh * kS;

  __shared__ ushort Klds[2 * BN * kDH];
  __shared__ ushort Vlds[2 * kDH * BN];
  __shared__ ushort Plds[4][16 * BN];

  const char* __restrict__ KgBase = reinterpret_cast<const char*>(Kb + bhS * 128);
  const char* __restrict__ VgBase = reinterpret_cast<const char*>(Vtb + (size_t)bh * 128 * kS);

  bf16x8 qf[4];
  {
    const float scale = 0.08838834764831845f;
    const float* qrow = qg + ((size_t)b * kS + rowbase + l15) * kE + h * kDH;
#pragma unroll
    for (int ks = 0; ks < 4; ++ks) {
      const float4 lo = *reinterpret_cast<const float4*>(qrow + ks * 32 + g * 8);
      const float4 hi = *reinterpret_cast<const float4*>(qrow + ks * 32 + g * 8 + 4);
      bf16x8 f;
      f[0] = (short)f2bf(lo.x * scale); f[1] = (short)f2bf(lo.y * scale);
      f[2] = (short)f2bf(lo.z * scale); f[3] = (short)f2bf(lo.w * scale);
      f[4] = (short)f2bf(hi.x * scale); f[5] = (short)f2bf(hi.y * scale);
      f[6] = (short)f2bf(hi.z * scale); f[7] = (short)f2bf(hi.w * scale);
      qf[ks] = f;
    }
  }
  float M2row[4];
#pragma unroll
  for (int reg = 0; reg < 4; ++reg) M2row[reg] = M2[bhS + rowbase + g * 4 + reg];

  int koffG[4], voffG[4];
#pragma unroll
  for (int i = 0; i < 4; ++i) {
    const int L = tid * 16 + i * 4096;
    { const int j = L >> 8, c = (L >> 4) & 15;
      koffG[i] = j * 256 + ((c ^ (j & 7)) << 4); }
    { const int d = L >> 7, c = (L >> 4) & 7;
      voffG[i] = d * 4096 + ((c ^ (d & 7)) << 4); }
  }

  auto stage = [&](int buf, int jt) {
    const char* Kg = KgBase + (size_t)jt * 16384;
    const char* Vg = VgBase + (size_t)jt * 128;
    char* kl = reinterpret_cast<char*>(Klds) + buf * 16384 + tid * 16;
    char* vl = reinterpret_cast<char*>(Vlds) + buf * 16384 + tid * 16;
#pragma unroll
    for (int i = 0; i < 4; ++i) gload16(Kg + koffG[i], kl + i * 4096);
#pragma unroll
    for (int i = 0; i < 4; ++i) gload16(Vg + voffG[i], vl + i * 4096);
  };

  f32x4 hacc[8];
#pragma unroll
  for (int db = 0; db < 8; ++db) hacc[db] = (f32x4){0.f, 0.f, 0.f, 0.f};
  float rs[4] = {0.f, 0.f, 0.f, 0.f};

  float avc[4];
#pragma unroll
  for (int cb = 0; cb < 4; ++cb) avc[cb] = a2[bhS + j0 * 64 + cb * 16 + l15];
  stage(0, j0);
  __syncthreads();

  for (int jt = j0; jt <= j1; ++jt) {
    const int cur = (jt - j0) & 1;
    float avn[4];
    if (jt < j1) {
      stage(cur ^ 1, jt + 1);
#pragma unroll
      for (int cb = 0; cb < 4; ++cb)
        avn[cb] = a2[bhS + (jt + 1) * 64 + cb * 16 + l15];
    }

    const int kbase = cur * 16384;
    f32x4 sacc[4];
#pragma unroll
    for (int cb = 0; cb < 4; ++cb) sacc[cb] = (f32x4){0.f, 0.f, 0.f, 0.f};
#pragma unroll
    for (int ks = 0; ks < 4; ++ks) {
#pragma unroll
      for (int cb = 0; cb < 4; ++cb) {
        const int j = cb * 16 + l15;
        const int kb = kbase + j * 256 + ((ks * 64 + g * 16) ^ ((l15 & 7) << 4));
        const bf16x8 kf = *reinterpret_cast<const bf16x8*>(
            reinterpret_cast<const char*>(Klds) + kb);
        sacc[cb] = __builtin_amdgcn_mfma_f32_16x16x32_bf16(qf[ks], kf, sacc[cb], 0, 0, 0);
      }
    }

#pragma unroll
    for (int cb = 0; cb < 4; ++cb) {
      const int jg = jt * 64 + cb * 16 + l15;
#pragma unroll
      for (int reg = 0; reg < 4; ++reg) {
        const int ig = rowbase + g * 4 + reg;
        float val = 0.f;
        if (jg <= ig) val = sacc[cb][reg] * exp2f(avc[cb] - M2row[reg]);
        rs[reg] += val;
        const int r = g * 4 + reg;
        const int pb = r * 128 + ((cb * 32 + l15 * 2) ^ ((r & 7) << 4));
        *reinterpret_cast<ushort*>(
            reinterpret_cast<char*>(&Plds[w][0]) + pb) = f2bf(val);
      }
    }

    const int vbase = cur * 16384;
#pragma unroll
    for (int ks2 = 0; ks2 < 2; ++ks2) {
      const int pbyte = l15 * 128 + ((ks2 * 64 + g * 16) ^ ((l15 & 7) << 4));
      const bf16x8 pf = *reinterpret_cast<const bf16x8*>(
          reinterpret_cast<const char*>(&Plds[w][0]) + pbyte);
#pragma unroll
      for (int db = 0; db < 8; ++db) {
        const int d = db * 16 + l15;
        const int vb = vbase + d * 128 + ((ks2 * 64 + g * 16) ^ ((d & 7) << 4));
        const bf16x8 vf = *reinterpret_cast<const bf16x8*>(
            reinterpret_cast<const char*>(Vlds) + vb);
        hacc[db] = __builtin_amdgcn_mfma_f32_16x16x32_bf16(vf, pf, hacc[db], 0, 0, 0);
      }
    }
    __syncthreads();
    if (jt < j1) {
#pragma unroll
      for (int cb = 0; cb < 4; ++cb) avc[cb] = avn[cb];
    }
  }

  // rowsum reduce over the 16 j-lanes
#pragma unroll
  for (int reg = 0; reg < 4; ++reg) {
    float x = rs[reg];
    x += __shfl_xor(x, 1); x += __shfl_xor(x, 2);
    x += __shfl_xor(x, 4); x += __shfl_xor(x, 8);
    rs[reg] = x;
  }

  if (chunk >= 0) {
    // write partials: hacc thread-linear, rs per local row
    float* pdst = ph + (size_t)chunk * (BM * kDH) + tid * 32;
#pragma unroll
    for (int db = 0; db < 8; ++db)
      *reinterpret_cast<float4*>(pdst + db * 4) =
          make_float4(hacc[db][0], hacc[db][1], hacc[db][2], hacc[db][3]);
    if (l15 == 0) {
#pragma unroll
      for (int reg = 0; reg < 4; ++reg)
        prs[chunk * BM + w * 16 + g * 4 + reg] = rs[reg];
    }
    return;
  }

  // inline epilogue (unsplit tiles)
  float* rsp = reinterpret_cast<float*>(&Plds[w][0]);
  if (l15 == 0) {
#pragma unroll
    for (int reg = 0; reg < 4; ++reg) rsp[g * 4 + reg] = rs[reg];
  }
  const float rsum = rsp[l15];
  const float nf = nfl[bhS + rowbase + l15];
  epilogue_store(hacc, rsum, nf, b, h, rowbase + l15, g, nw, out);
}

// ---------------- combine: add the two chunk partials, run epilogue ----------------
__global__ __launch_bounds__(256) void combine_kernel(
    const float* __restrict__ ph, const float* __restrict__ prs,
    const float* __restrict__ nfl, const float* __restrict__ nw,
    float* __restrict__ out) {
  const int blk = blockIdx.x;          // bh*16 + t
  const int bh = blk >> 4, t = blk & 15;
  const int b = bh >> 3, h = bh & 7;
  const int it = kHeavy + t;
  const int tid = threadIdx.x;
  const int w = tid >> 6, lane = tid & 63;
  const int l15 = lane & 15, g = lane >> 4;
  const int rowbase = it * BM + w * 16;
  const int c0 = blk * 2, c1 = blk * 2 + 1;

  f32x4 hacc[8];
  const float* p0 = ph + (size_t)c0 * (BM * kDH) + tid * 32;
  const float* p1 = ph + (size_t)c1 * (BM * kDH) + tid * 32;
#pragma unroll
  for (int db = 0; db < 8; ++db) {
    const float4 a = *reinterpret_cast<const float4*>(p0 + db * 4);
    const float4 c = *reinterpret_cast<const float4*>(p1 + db * 4);
    hacc[db] = (f32x4){a.x + c.x, a.y + c.y, a.z + c.z, a.w + c.w};
  }
  const float rsum = prs[c0 * BM + w * 16 + l15] + prs[c1 * BM + w * 16 + l15];
  const float nf = nfl[(size_t)bh * kS + rowbase + l15];
  epilogue_store(hacc, rsum, nf, b, h, rowbase + l15, g, nw, out);
}

extern "C" void kernel_launch(void* const* d_in, const int* in_sizes, int n_in,
                              void* d_out, int out_size, void* d_ws, size_t ws_size,
                              hipStream_t stream) {
  const float* q  = (const float*)d_in[0];
  const float* k  = (const float*)d_in[1];
  const float* v  = (const float*)d_in[2];
  const float* iw = (const float*)d_in[3];
  const float* ib = (const float*)d_in[4];
  const float* fw = (const float*)d_in[5];
  const float* fb = (const float*)d_in[6];
  const float* nw = (const float*)d_in[7];
  float* out = (float*)d_out;

  char* ws = (char*)d_ws;
  const int BHS = kB * kNH * kS;                 // 32768
  float* i_pre = (float*)ws;
  float* f_pre = i_pre + BHS;
  float* a2    = i_pre + 2 * BHS;
  float* M2    = i_pre + 3 * BHS;
  float* nfl   = i_pre + 4 * BHS;
  char* ws2 = ws + (size_t)5 * BHS * 4;
  ushort* Kb  = (ushort*)ws2;                              // 8.39 MB
  ushort* Vtb = Kb + (size_t)kB * kNH * kS * kDH;          // 8.39 MB
  float* ph   = (float*)(Vtb + (size_t)kB * kNH * kS * kDH);  // 512*32KB = 16.8 MB
  float* prs  = ph + (size_t)512 * BM * kDH;               // 131 KB

  convkv_kernel<<<dim3(kS / 8, kB), dim3(256), 0, stream>>>(k, v, Kb, Vtb);
  gates_kernel<<<dim3(kB * kS / 8), dim3(256), 0, stream>>>(q, k, v, iw, ib, fw, fb,
                                                            i_pre, f_pre);
  scan_kernel<<<dim3(kB * kNH), dim3(256), 0, stream>>>(i_pre, f_pre, a2, M2, nfl);
  attn_mfma_kernel<<<dim3(kUnits, kB * kNH), dim3(256), 0, stream>>>(
      q, Kb, Vtb, a2, M2, nfl, nw, out, ph, prs);
  combine_kernel<<<dim3(kB * kNH * 16), dim3(256), 0, stream>>>(ph, prs, nfl, nw, out);
}

// Round 7
// 118.447 us; speedup vs baseline: 62.2819x; 1.0333x over previous
//
#include <hip/hip_runtime.h>
#include <hip/hip_bf16.h>
#include <math.h>

typedef __attribute__((ext_vector_type(8))) short bf16x8;
typedef __attribute__((ext_vector_type(16))) float f32x16;

namespace {
constexpr int kB = 2, kS = 2048, kE = 1024, kNH = 8, kDH = 128, kE3 = 3072;
constexpr float kLog2e = 1.4426950408889634f;
constexpr int kUnits = 27;        // work units per bh (chunks of <=14 kv-steps)
constexpr int kSplitPerBh = 20;   // partial chunks per bh
}

// units sorted by descending step count (heavy first)
__device__ const int kOrder[kUnits] = {6,19,20,17,18,5,15,16,13,14,24,25,4,
                                       11,12,21,22,23,26,9,10,3,7,8,2,1,0};

__device__ __forceinline__ ushort f2bf(float x) {
  union { __hip_bfloat16 b; ushort u; } c; c.b = __float2bfloat16(x); return c.u;
}
__device__ __forceinline__ uint pk2(float a, float b) {
  return (uint)f2bf(a) | ((uint)f2bf(b) << 16);
}
__device__ __forceinline__ void gload16(const void* g, void* l) {
  __builtin_amdgcn_global_load_lds(
      (const __attribute__((address_space(1))) void*)g,
      (__attribute__((address_space(3))) void*)l, 16, 0, 0);
}
__device__ __forceinline__ f32x16 zero16() {
  f32x16 z;
#pragma unroll
  for (int i = 0; i < 16; ++i) z[i] = 0.f;
  return z;
}
union UB8 { uint4 u; bf16x8 f; };

__device__ __forceinline__ float butterfly64(float* acc, int lane) {
  int cur = 64;
#pragma unroll
  for (int lv = 0; lv < 6; ++lv) {
    const int bmask = 1 << lv;
    const int half = cur >> 1;
    const bool hi = (lane & bmask) != 0;
#pragma unroll
    for (int i = 0; i < 32; ++i) {
      if (i >= half) break;
      const float keep = hi ? acc[i + half] : acc[i];
      const float send = hi ? acc[i] : acc[i + half];
      acc[i] = keep + __shfl_xor(send, bmask);
    }
    cur = half;
  }
  return acc[0];
}

// ---------------- gates: 8 tokens/block; waves split (gate-half x K-half) ----------------
__global__ __launch_bounds__(256) void gates_kernel(
    const float* __restrict__ q, const float* __restrict__ k, const float* __restrict__ v,
    const float* __restrict__ iw, const float* __restrict__ ib,
    const float* __restrict__ fw, const float* __restrict__ fb,
    float* __restrict__ i_pre, float* __restrict__ f_pre) {
  const int tid = threadIdx.x;
  const int w = tid >> 6, lane = tid & 63;
  const int tokbase = blockIdx.x * 8;
  const int kh = w >> 1, gh = w & 1;
  const float* __restrict__ W = gh ? fw : iw;

  float acc[64];
#pragma unroll
  for (int i = 0; i < 64; ++i) acc[i] = 0.f;

  for (int step = 0; step < 24; ++step) {
    const int e = kh * 1536 + step * 64 + lane;
    const int seg = e >> 10;
    const int eo = e & 1023;
    const float* __restrict__ src = (seg == 0) ? q : (seg == 1) ? k : v;
    float gv[8];
#pragma unroll
    for (int t = 0; t < 8; ++t)
      gv[t] = src[(size_t)(tokbase + t) * kE + eo];
    float w8[8];
#pragma unroll
    for (int hh = 0; hh < 8; ++hh) w8[hh] = W[hh * kE3 + e];
#pragma unroll
    for (int t = 0; t < 8; ++t)
#pragma unroll
      for (int hh = 0; hh < 8; ++hh)
        acc[t * 8 + hh] += gv[t] * w8[hh];
  }
  const float r = butterfly64(acc, lane);
  const int a = ((lane & 1) << 5) | ((lane & 2) << 3) | ((lane & 4) << 1) |
                ((lane & 8) >> 1) | ((lane & 16) >> 3) | ((lane & 32) >> 5);
  __shared__ float red[4][64];
  red[w][a] = r;
  __syncthreads();
  if (tid < 128) {
    const int t = tid >> 4, g16 = tid & 15, hh = g16 & 7;
    const float val = (g16 < 8) ? red[0][t * 8 + hh] + red[2][t * 8 + hh]
                                : red[1][t * 8 + hh] + red[3][t * 8 + hh];
    const int token = tokbase + t;
    const int b = token >> 11, s = token & 2047;
    const size_t idx = ((size_t)(b * 8 + hh)) * kS + s;
    if (g16 < 8) i_pre[idx] = val + ib[hh];
    else         f_pre[idx] = val + fb[hh];
  }
}

// ---------------- scan: wt (f32, exact), M2 (log2), nfl, per-64-tile max Cg ----------------
__global__ __launch_bounds__(256) void scan_kernel(
    const float* __restrict__ i_pre, const float* __restrict__ f_pre,
    float* __restrict__ wt_out, float* __restrict__ M2_out, float* __restrict__ nfl_out,
    float* __restrict__ Cg) {
  const int bh = blockIdx.x;
  const int tid = threadIdx.x;
  const int w = tid >> 6, lane = tid & 63;
  __shared__ float wsum[4], wmax[4];
  const float* __restrict__ fp = f_pre + (size_t)bh * kS;
  const float* __restrict__ ip = i_pre + (size_t)bh * kS;
  const int s0 = tid * 8;

  const float4 fa = *reinterpret_cast<const float4*>(fp + s0);
  const float4 fb4 = *reinterpret_cast<const float4*>(fp + s0 + 4);
  float lf[8];
  {
    const float fv[8] = {fa.x, fa.y, fa.z, fa.w, fb4.x, fb4.y, fb4.z, fb4.w};
#pragma unroll
    for (int j = 0; j < 8; ++j)
      lf[j] = fminf(fv[j], 0.f) - log1pf(expf(-fabsf(fv[j])));
  }
  float run = 0.f, pcs[8];
#pragma unroll
  for (int j = 0; j < 8; ++j) { run += lf[j]; pcs[j] = run; }
  float x = run;
#pragma unroll
  for (int d = 1; d < 64; d <<= 1) {
    const float t = __shfl_up(x, d);
    if (lane >= d) x += t;
  }
  if (lane == 63) wsum[w] = x;
  __syncthreads();
  float woff = 0.f;
#pragma unroll
  for (int i = 0; i < 4; ++i) if (i < w) woff += wsum[i];
  const float csbase = woff + x - run;
  float cs[8];
#pragma unroll
  for (int j = 0; j < 8; ++j) cs[j] = csbase + pcs[j];

  const float4 ia = *reinterpret_cast<const float4*>(ip + s0);
  const float4 ib4 = *reinterpret_cast<const float4*>(ip + s0 + 4);
  float av[8];
  {
    const float iv[8] = {ia.x, ia.y, ia.z, ia.w, ib4.x, ib4.y, ib4.z, ib4.w};
#pragma unroll
    for (int j = 0; j < 8; ++j) av[j] = iv[j] - cs[j];
  }
  float rmax = -1e30f, pm[8];
#pragma unroll
  for (int j = 0; j < 8; ++j) { rmax = fmaxf(rmax, av[j]); pm[j] = rmax; }

  // per-64-token tile max (tiles = 8 consecutive tids); butterfly leaves max in all lanes
  float tm = rmax;
  tm = fmaxf(tm, __shfl_xor(tm, 1));
  tm = fmaxf(tm, __shfl_xor(tm, 2));
  tm = fmaxf(tm, __shfl_xor(tm, 4));
  if ((lane & 7) == 0) Cg[bh * 32 + (tid >> 3)] = tm * kLog2e;

  // wt = exp2(a2 - Cseg), exact f32
  float4 wtlo, wthi;
  wtlo.x = exp2f((av[0] - tm) * kLog2e); wtlo.y = exp2f((av[1] - tm) * kLog2e);
  wtlo.z = exp2f((av[2] - tm) * kLog2e); wtlo.w = exp2f((av[3] - tm) * kLog2e);
  wthi.x = exp2f((av[4] - tm) * kLog2e); wthi.y = exp2f((av[5] - tm) * kLog2e);
  wthi.z = exp2f((av[6] - tm) * kLog2e); wthi.w = exp2f((av[7] - tm) * kLog2e);

  float mi = rmax;
#pragma unroll
  for (int d = 1; d < 64; d <<= 1) {
    const float t = __shfl_up(mi, d);
    if (lane >= d) mi = fmaxf(mi, t);
  }
  if (lane == 63) wmax[w] = mi;
  float mexcl = __shfl_up(mi, 1);
  if (lane == 0) mexcl = -1e30f;
  __syncthreads();
  float wmoff = -1e30f;
#pragma unroll
  for (int i = 0; i < 4; ++i) if (i < w) wmoff = fmaxf(wmoff, wmax[i]);
  const float mbase = fmaxf(wmoff, mexcl);

  float M[8];
#pragma unroll
  for (int j = 0; j < 8; ++j) M[j] = fmaxf(mbase, pm[j]);
  float4 m2lo, m2hi, nflo, nfhi;
  m2lo.x = M[0] * kLog2e; m2lo.y = M[1] * kLog2e; m2lo.z = M[2] * kLog2e; m2lo.w = M[3] * kLog2e;
  m2hi.x = M[4] * kLog2e; m2hi.y = M[5] * kLog2e; m2hi.z = M[6] * kLog2e; m2hi.w = M[7] * kLog2e;
  nflo.x = expf(-(cs[0] + M[0])); nflo.y = expf(-(cs[1] + M[1]));
  nflo.z = expf(-(cs[2] + M[2])); nflo.w = expf(-(cs[3] + M[3]));
  nfhi.x = expf(-(cs[4] + M[4])); nfhi.y = expf(-(cs[5] + M[5]));
  nfhi.z = expf(-(cs[6] + M[6])); nfhi.w = expf(-(cs[7] + M[7]));
  const size_t o = (size_t)bh * kS + s0;
  *reinterpret_cast<float4*>(wt_out + o) = wtlo;
  *reinterpret_cast<float4*>(wt_out + o + 4) = wthi;
  *reinterpret_cast<float4*>(M2_out + o) = m2lo;
  *reinterpret_cast<float4*>(M2_out + o + 4) = m2hi;
  *reinterpret_cast<float4*>(nfl_out + o) = nflo;
  *reinterpret_cast<float4*>(nfl_out + o + 4) = nfhi;
}

// ---------------- convkv: Kb bf16 head-major + Vt bf16 transposed ----------------
__global__ __launch_bounds__(256) void convkv_kernel(
    const float* __restrict__ k, const float* __restrict__ v,
    ushort* __restrict__ Kb, ushort* __restrict__ Vtb) {
  const int b = blockIdx.y;
  const int s0 = blockIdx.x * 8;
  const int tid = threadIdx.x;
  const int w = tid >> 6, lane = tid & 63;
  __shared__ ushort Vst[8 * 1024];

#pragma unroll
  for (int t = 0; t < 2; ++t) {
    const int tokl = w * 2 + t;
    const int s = s0 + tokl;
    const size_t base = ((size_t)b * kS + s) * kE + lane * 16;
    const int hh = lane >> 3;

    const float4 k0 = *reinterpret_cast<const float4*>(k + base);
    const float4 k1 = *reinterpret_cast<const float4*>(k + base + 4);
    const float4 k2 = *reinterpret_cast<const float4*>(k + base + 8);
    const float4 k3 = *reinterpret_cast<const float4*>(k + base + 12);
    uint4 pa, pb;
    pa.x = pk2(k0.x, k0.y); pa.y = pk2(k0.z, k0.w);
    pa.z = pk2(k1.x, k1.y); pa.w = pk2(k1.z, k1.w);
    pb.x = pk2(k2.x, k2.y); pb.y = pk2(k2.z, k2.w);
    pb.z = pk2(k3.x, k3.y); pb.w = pk2(k3.z, k3.w);
    ushort* kd = Kb + ((size_t)(b * 8 + hh) * kS + s) * 128 + (lane & 7) * 16;
    *reinterpret_cast<uint4*>(kd) = pa;
    *reinterpret_cast<uint4*>(kd + 8) = pb;

    const float4 v0 = *reinterpret_cast<const float4*>(v + base);
    const float4 v1 = *reinterpret_cast<const float4*>(v + base + 4);
    const float4 v2 = *reinterpret_cast<const float4*>(v + base + 8);
    const float4 v3 = *reinterpret_cast<const float4*>(v + base + 12);
    uint4 va, vb4;
    va.x = pk2(v0.x, v0.y); va.y = pk2(v0.z, v0.w);
    va.z = pk2(v1.x, v1.y); va.w = pk2(v1.z, v1.w);
    vb4.x = pk2(v2.x, v2.y); vb4.y = pk2(v2.z, v2.w);
    vb4.z = pk2(v3.x, v3.y); vb4.w = pk2(v3.z, v3.w);
    const int cc0 = lane * 2, cc1 = lane * 2 + 1;
    *reinterpret_cast<uint4*>(reinterpret_cast<char*>(Vst) + tokl * 2048 +
                              ((cc0 ^ ((cc0 >> 3) & 7)) << 4)) = va;
    *reinterpret_cast<uint4*>(reinterpret_cast<char*>(Vst) + tokl * 2048 +
                              ((cc1 ^ ((cc1 >> 3) & 7)) << 4)) = vb4;
  }
  __syncthreads();

#pragma unroll
  for (int j = 0; j < 4; ++j) {
    const int e = j * 256 + tid;
    const int cc = e >> 3;
    const int off = ((cc ^ ((cc >> 3) & 7)) << 4) + (e & 7) * 2;
    uint tmp[4];
#pragma unroll
    for (int t2 = 0; t2 < 8; t2 += 2) {
      const ushort u0 = *reinterpret_cast<const ushort*>(
          reinterpret_cast<const char*>(Vst) + t2 * 2048 + off);
      const ushort u1 = *reinterpret_cast<const ushort*>(
          reinterpret_cast<const char*>(Vst) + (t2 + 1) * 2048 + off);
      tmp[t2 >> 1] = (uint)u0 | ((uint)u1 << 16);
    }
    uint4 o; o.x = tmp[0]; o.y = tmp[1]; o.z = tmp[2]; o.w = tmp[3];
    ushort* vd = Vtb + ((size_t)(b * 8 + (e >> 7)) * 128 + (e & 127)) * kS + s0;
    *reinterpret_cast<uint4*>(vd) = o;
  }
}

// ---------------- attn: 32x32 MFMA, swapped QK, in-register P, f32 decay ----------------
__global__ __launch_bounds__(256, 2) void attn_mfma_kernel(
    const float* __restrict__ qg, const ushort* __restrict__ Kb,
    const ushort* __restrict__ Vtb, const float* __restrict__ wt,
    const float* __restrict__ Cg, const float* __restrict__ M2,
    const float* __restrict__ nfl, const float* __restrict__ nw,
    float* __restrict__ out, float* __restrict__ ph, float* __restrict__ prs) {
  const int bh = blockIdx.y;
  const int b = bh >> 3, h = bh & 7;
  const int u = kOrder[blockIdx.x];
  int it, j0, j1, cid = -1;
  if (u <= 6) { it = u; const int T = 2 * it + 2; j0 = 0; j1 = T - 1; }
  else if (u <= 20) {
    const int s = u - 7; it = 7 + (s >> 1); const int ci = s & 1;
    const int T = 2 * it + 2;
    j0 = (T * ci) >> 1; j1 = ((T * (ci + 1)) >> 1) - 1;
    cid = bh * kSplitPerBh + (u - 7);
  } else {
    const int s = u - 21; it = 14 + (s >= 3 ? 1 : 0); const int ci = s - (s >= 3 ? 3 : 0);
    const int T = 2 * it + 2;
    j0 = (T * ci) / 3; j1 = (T * (ci + 1)) / 3 - 1;
    cid = bh * kSplitPerBh + (u - 7);
  }
  const int tid = threadIdx.x;
  const int w = tid >> 6, lane = tid & 63;
  const int l31 = lane & 31, hi = lane >> 5;
  const int row_w = it * 128 + w * 32;      // wave's first q row
  const int ig = row_w + l31;               // q row (lane-owned column in S^T)
  const size_t bhS = (size_t)bh * kS;

  __shared__ ushort Klds[2 * 64 * 128];   // [buf][j][d], 256B rows, col16 ^ (j&15)
  __shared__ ushort Vlds[2 * 128 * 64];   // [buf][d][j], 128B rows, col16 ^ (d&7)
  __shared__ float Wlds[2 * 64];          // [buf][j] decay weights (f32)
  __shared__ float rsx[4][32];

  const char* __restrict__ KgBase = reinterpret_cast<const char*>(Kb + bhS * 128);
  const char* __restrict__ VgBase = reinterpret_cast<const char*>(Vtb + (size_t)bh * 128 * kS);
  const char* __restrict__ WgBase = reinterpret_cast<const char*>(wt + bhS);

  // Q fragments: B[k=d][col=i], lane col = l31, k = 16ks + 8hi + 0..7
  bf16x8 qf[8];
  {
    const float scale = 0.08838834764831845f;
    const float* qrow = qg + ((size_t)b * kS + ig) * kE + h * kDH;
#pragma unroll
    for (int ks = 0; ks < 8; ++ks) {
      const int d0 = ks * 16 + hi * 8;
      const float4 lo = *reinterpret_cast<const float4*>(qrow + d0);
      const float4 hi4 = *reinterpret_cast<const float4*>(qrow + d0 + 4);
      UB8 f;
      f.u.x = pk2(lo.x * scale, lo.y * scale);
      f.u.y = pk2(lo.z * scale, lo.w * scale);
      f.u.z = pk2(hi4.x * scale, hi4.y * scale);
      f.u.w = pk2(hi4.z * scale, hi4.w * scale);
      qf[ks] = f.f;
    }
  }
  const float M2i = M2[bhS + ig];

  // pre-swizzled global source offsets (LDS dest linear)
  int koffG[4], voffG[4];
#pragma unroll
  for (int i = 0; i < 4; ++i) {
    const int L = tid * 16 + i * 4096;
    { const int j = L >> 8, c = (L >> 4) & 15;
      koffG[i] = j * 256 + ((c ^ (j & 15)) << 4); }
    { const int d = L >> 7, c = (L >> 4) & 7;
      voffG[i] = d * 4096 + ((c ^ (d & 7)) << 4); }
  }
  auto stage = [&](int buf, int jt) {
    const char* Kg = KgBase + (size_t)jt * 16384;
    const char* Vg = VgBase + (size_t)jt * 128;
    char* kl = reinterpret_cast<char*>(Klds) + buf * 16384 + tid * 16;
    char* vl = reinterpret_cast<char*>(Vlds) + buf * 16384 + tid * 16;
#pragma unroll
    for (int i = 0; i < 4; ++i) gload16(Kg + koffG[i], kl + i * 4096);
#pragma unroll
    for (int i = 0; i < 4; ++i) gload16(Vg + voffG[i], vl + i * 4096);
    if (tid < 16)
      gload16(WgBase + jt * 256 + tid * 16,
              reinterpret_cast<char*>(Wlds) + buf * 256 + tid * 16);
  };

  f32x16 hacc[4];
#pragma unroll
  for (int dc = 0; dc < 4; ++dc) hacc[dc] = zero16();
  float rs = 0.f;

  stage(0, j0);
  __syncthreads();

  for (int jt = j0; jt <= j1; ++jt) {
    const int cur = (jt - j0) & 1;
    if (jt < j1) stage(cur ^ 1, jt + 1);
    const int jlo = jt * 64;
    const bool v0 = (jlo <= row_w + 31);
    const bool v1 = (jlo + 32 <= row_w + 31);
    const bool fullmask = (jlo + 63 <= row_w);   // entire tile causally valid

    if (v0) {
      const float f = exp2f(Cg[bh * 32 + jt] - M2i);
      const char* kb = reinterpret_cast<const char*>(Klds) + cur * 16384;
      const char* vb = reinterpret_cast<const char*>(Vlds) + cur * 16384;
      const float* Wf = Wlds + cur * 64;
      const int ksw = (l31 & 15) << 4;

      // ---- swapped QK: S^T[j][i], rows j in regs, col i = l31 ----
      f32x16 sacc0 = zero16(), sacc1 = zero16();
#pragma unroll
      for (int ks = 0; ks < 8; ++ks) {
        const int colb = 32 * ks + 16 * hi;
        const bf16x8 kf0 = *reinterpret_cast<const bf16x8*>(
            kb + l31 * 256 + (colb ^ ksw));
        sacc0 = __builtin_amdgcn_mfma_f32_32x32x16_bf16(kf0, qf[ks], sacc0, 0, 0, 0);
        if (v1) {
          const bf16x8 kf1 = *reinterpret_cast<const bf16x8*>(
              kb + (32 + l31) * 256 + (colb ^ ksw));
          sacc1 = __builtin_amdgcn_mfma_f32_32x32x16_bf16(kf1, qf[ks], sacc1, 0, 0, 0);
        }
      }

      // ---- P = S' * wt[j] * f (exact f32 decay; mask on diagonal) ----
      uint pkw[2][8];
#pragma unroll
      for (int jc = 0; jc < 2; ++jc) {
        if (jc == 1 && !v1) break;
        const f32x16 sa = jc ? sacc1 : sacc0;
        float p[16];
#pragma unroll
        for (int r = 0; r < 16; ++r) {
          const int joff = jc * 32 + (r & 3) + 8 * (r >> 2) + 4 * hi;
          float val = sa[r] * (Wf[joff] * f);
          if (!fullmask) val = (jlo + joff <= ig) ? val : 0.f;
          rs += val; p[r] = val;
        }
#pragma unroll
        for (int q2 = 0; q2 < 8; ++q2) pkw[jc][q2] = pk2(p[2 * q2], p[2 * q2 + 1]);
      }

      // ---- PV: H[i][d] (rows i in regs, col d = l31) ----
#pragma unroll
      for (int ks = 0; ks < 4; ++ks) {
        const int jc = ks >> 1, ks2 = ks & 1;
        if (jc == 1 && !v1) break;
        UB8 pf;
        pf.u.x = pkw[jc][ks2 * 4 + 0]; pf.u.y = pkw[jc][ks2 * 4 + 1];
        pf.u.z = pkw[jc][ks2 * 4 + 2]; pf.u.w = pkw[jc][ks2 * 4 + 3];
        const int colb = 64 * jc + 32 * ks2 + 8 * hi;
#pragma unroll
        for (int dc = 0; dc < 4; ++dc) {
          const int d = dc * 32 + l31;
          const char* vrow = vb + d * 128;
          const int sw = (d & 7) << 4;
          const uint2 a = *reinterpret_cast<const uint2*>(vrow + (colb ^ sw));
          const uint2 c = *reinterpret_cast<const uint2*>(vrow + ((colb + 16) ^ sw));
          UB8 vf; vf.u.x = a.x; vf.u.y = a.y; vf.u.z = c.x; vf.u.w = c.y;
          hacc[dc] = __builtin_amdgcn_mfma_f32_32x32x16_bf16(pf.f, vf.f, hacc[dc], 0, 0, 0);
        }
      }
    }
    __syncthreads();   // drains staging; next buffer ready
  }

  const float rs_tot = rs + __shfl_xor(rs, 32);

  if (cid >= 0) {
    float* pb = ph + (size_t)cid * 16384;
#pragma unroll
    for (int dc = 0; dc < 4; ++dc)
#pragma unroll
      for (int r = 0; r < 16; ++r) {
        const int il = w * 32 + (r & 3) + 8 * (r >> 2) + 4 * hi;
        pb[il * 128 + dc * 32 + l31] = hacc[dc][r];
      }
    if (hi == 0) prs[cid * 128 + w * 32 + l31] = rs_tot;
    return;
  }

  // ---- inline epilogue (unsplit tiles) ----
  if (hi == 0) rsx[w][l31] = rs_tot;
  float nwv[4];
#pragma unroll
  for (int dc = 0; dc < 4; ++dc) nwv[dc] = nw[h * kDH + dc * 32 + l31];
#pragma unroll
  for (int r = 0; r < 16; ++r) {
    const int imap = (r & 3) + 8 * (r >> 2) + 4 * hi;
    const float rsum = rsx[w][imap];
    const float nf = nfl[bhS + row_w + imap];
    const float inv = 1.f / (fmaxf(fabsf(rsum), nf) + 1e-6f);
    float hv[4];
    float s1 = 0.f, s2 = 0.f;
#pragma unroll
    for (int dc = 0; dc < 4; ++dc) {
      hv[dc] = hacc[dc][r] * inv;
      s1 += hv[dc]; s2 += hv[dc] * hv[dc];
    }
#pragma unroll
    for (int off = 1; off <= 16; off <<= 1) {
      s1 += __shfl_xor(s1, off);
      s2 += __shfl_xor(s2, off);
    }
    const float mu = s1 * (1.f / 128.f);
    const float var = s2 * (1.f / 128.f) - mu * mu;
    const float rstd = rsqrtf(var + 1e-5f);
    float* __restrict__ orow = out + ((size_t)b * kS + row_w + imap) * kE + h * kDH;
#pragma unroll
    for (int dc = 0; dc < 4; ++dc)
      orow[dc * 32 + l31] = (hv[dc] - mu) * rstd * nwv[dc];
  }
}

// ---------------- combine: sum chunk partials, normalize, groupnorm, store ----------------
__global__ __launch_bounds__(256) void combine_kernel(
    const float* __restrict__ ph, const float* __restrict__ prs,
    const float* __restrict__ nfl, const float* __restrict__ nw,
    float* __restrict__ out) {
  const int blk = blockIdx.x;
  const int bh = blk / 9, ct = blk % 9;
  const int b = bh >> 3, h = bh & 7;
  const int it = 7 + ct;
  const int nc = (ct < 7) ? 2 : 3;
  const int cb0 = bh * kSplitPerBh + ((ct < 7) ? ct * 2 : 14 + (ct - 7) * 3);
  const int tid = threadIdx.x;
  __shared__ float sinv[128];
  if (tid < 128) {
    float rsum = 0.f;
    for (int c = 0; c < nc; ++c) rsum += prs[(cb0 + c) * 128 + tid];
    const float nf = nfl[(size_t)bh * kS + it * 128 + tid];
    sinv[tid] = 1.f / (fmaxf(fabsf(rsum), nf) + 1e-6f);
  }
  __syncthreads();
  for (int kk = 0; kk < 16; ++kk) {
    const int idx = kk * 256 + tid;
    const int row = idx >> 5, c4 = idx & 31;
    float ax = 0.f, ay = 0.f, az = 0.f, aw = 0.f;
    for (int c = 0; c < nc; ++c) {
      const float4 t = *reinterpret_cast<const float4*>(
          ph + (size_t)(cb0 + c) * 16384 + row * 128 + c4 * 4);
      ax += t.x; ay += t.y; az += t.z; aw += t.w;
    }
    const float inv = sinv[row];
    ax *= inv; ay *= inv; az *= inv; aw *= inv;
    float s1 = ax + ay + az + aw;
    float s2 = ax * ax + ay * ay + az * az + aw * aw;
#pragma unroll
    for (int off = 1; off <= 16; off <<= 1) {
      s1 += __shfl_xor(s1, off);
      s2 += __shfl_xor(s2, off);
    }
    const float mu = s1 * (1.f / 128.f);
    const float var = s2 * (1.f / 128.f) - mu * mu;
    const float rstd = rsqrtf(var + 1e-5f);
    const float4 nw4 = *reinterpret_cast<const float4*>(nw + h * kDH + c4 * 4);
    float4 o;
    o.x = (ax - mu) * rstd * nw4.x;
    o.y = (ay - mu) * rstd * nw4.y;
    o.z = (az - mu) * rstd * nw4.z;
    o.w = (aw - mu) * rstd * nw4.w;
    *reinterpret_cast<float4*>(
        out + ((size_t)b * kS + it * 128 + row) * kE + h * kDH + c4 * 4) = o;
  }
}

extern "C" void kernel_launch(void* const* d_in, const int* in_sizes, int n_in,
                              void* d_out, int out_size, void* d_ws, size_t ws_size,
                              hipStream_t stream) {
  const float* q  = (const float*)d_in[0];
  const float* k  = (const float*)d_in[1];
  const float* v  = (const float*)d_in[2];
  const float* iw = (const float*)d_in[3];
  const float* ib = (const float*)d_in[4];
  const float* fw = (const float*)d_in[5];
  const float* fb = (const float*)d_in[6];
  const float* nw = (const float*)d_in[7];
  float* out = (float*)d_out;

  char* ws = (char*)d_ws;
  const int BHS = kB * kNH * kS;                 // 32768
  float* i_pre = (float*)ws;
  float* f_pre = i_pre + BHS;
  float* wt    = i_pre + 2 * BHS;
  float* M2    = i_pre + 3 * BHS;
  float* nfl   = i_pre + 4 * BHS;
  float* Cg    = i_pre + 5 * BHS;                // 512 floats
  ushort* Kb  = (ushort*)(ws + (size_t)(5 * BHS + 512) * 4);
  ushort* Vtb = Kb + (size_t)kB * kNH * kS * kDH;          // +8.39MB
  float* ph   = (float*)(Vtb + (size_t)kB * kNH * kS * kDH);  // 320*64KB = 21MB
  float* prs  = ph + (size_t)320 * 128 * 128;

  gates_kernel<<<dim3(kB * kS / 8), dim3(256), 0, stream>>>(q, k, v, iw, ib, fw, fb,
                                                            i_pre, f_pre);
  scan_kernel<<<dim3(kB * kNH), dim3(256), 0, stream>>>(i_pre, f_pre, wt, M2, nfl, Cg);
  convkv_kernel<<<dim3(kS / 8, kB), dim3(256), 0, stream>>>(k, v, Kb, Vtb);
  attn_mfma_kernel<<<dim3(kUnits, kB * kNH), dim3(256), 0, stream>>>(
      q, Kb, Vtb, wt, Cg, M2, nfl, nw, out, ph, prs);
  combine_kernel<<<dim3(kB * kNH * 9), dim3(256), 0, stream>>>(ph, prs, nfl, nw, out);
}